// Round 10
// baseline (206.187 us; speedup 1.0000x reference)
//
#include <hip/hip_runtime.h>
#include <math.h>

#define HWSZ 4096   // 64*64
// 1/sqrt(32) * log2(e): scores come out pre-multiplied by log2(e), so softmax
// uses p = exp2(S) (single v_exp_f32) -- mathematically identical.
#define QSCALE_L2E 0.25501988932587245f

typedef __bf16 bf16x2 __attribute__((ext_vector_type(2)));
typedef __bf16 bf16x4 __attribute__((ext_vector_type(4)));
typedef __bf16 bf16x8 __attribute__((ext_vector_type(8)));
typedef float  f32x4  __attribute__((ext_vector_type(4)));

// ---------------- scrambled-token LayerNorm, strip version ----------------
__global__ __launch_bounds__(256) void ln_qn_kernel(
    const float* __restrict__ F, const float* __restrict__ lnw,
    const float* __restrict__ lnb, __bf16* __restrict__ qnb)
{
  __shared__ float sm[16*269];         // [c16] stride 269, [py] stride 67, [x]
  int blk = blockIdx.x;                // b*256 + wy*16 + t
  int b = blk >> 8, wy = (blk >> 4) & 15, t = blk & 15;
  int tid = threadIdx.x;
  const float* Fb = F + ((size_t)(b*256 + t*16))*HWSZ + (wy*4)*64;
  int py = tid >> 6, x = tid & 63;
  #pragma unroll
  for (int j = 0; j < 16; ++j)
    sm[j*269 + py*67 + x] = Fb[(size_t)j*HWSZ + py*64 + x];
  __syncthreads();
  int wx = tid >> 4, cl = tid & 15;    // window wx, channel-lane cl
  float vals[16], s1 = 0.f, s2 = 0.f;
  #pragma unroll
  for (int p = 0; p < 16; ++p) {
    float v = sm[cl*269 + (p >> 2)*67 + wx*4 + (p & 3)];
    vals[p] = v; s1 += v; s2 += v*v;
  }
  #pragma unroll
  for (int m = 1; m < 16; m <<= 1) { s1 += __shfl_xor(s1, m); s2 += __shfl_xor(s2, m); }
  float mean = s1 * (1.f/256.f);
  float var  = s2 * (1.f/256.f) - mean*mean;
  float rstd = rsqrtf(var + 1e-5f);
  __bf16* outp = qnb + (((size_t)(b*256 + wy*16 + wx))*16 + t)*256 + cl*16;
  bf16x8 o0, o1;
  #pragma unroll
  for (int p = 0; p < 8; ++p) {
    o0[p] = (__bf16)((vals[p]  -mean)*rstd*lnw[cl*16+p]   + lnb[cl*16+p]);
    o1[p] = (__bf16)((vals[p+8]-mean)*rstd*lnw[cl*16+p+8] + lnb[cl*16+p+8]);
  }
  *(bf16x8*)outp = o0;
  *(bf16x8*)(outp+8) = o1;
}

// ---------------- fused pools: thread = 2x2 mid patch -> 1 glb elem ----------------
__global__ __launch_bounds__(256) void pool_kernel(
    const float* __restrict__ F, float* __restrict__ mid, float* __restrict__ glb)
{
  int bc = blockIdx.x;                  // b*256 + c
  int t = threadIdx.x;
  int gy = t >> 4, gx = t & 15;
  const float* p = F + (size_t)bc*HWSZ + (gy*4)*64 + gx*4;
  float4 r0 = *(const float4*)(p);
  float4 r1 = *(const float4*)(p + 64);
  float4 r2 = *(const float4*)(p + 128);
  float4 r3 = *(const float4*)(p + 192);
  float m00 = 0.25f*(r0.x + r0.y + r1.x + r1.y);
  float m01 = 0.25f*(r0.z + r0.w + r1.z + r1.w);
  float m10 = 0.25f*(r2.x + r2.y + r3.x + r3.y);
  float m11 = 0.25f*(r2.z + r2.w + r3.z + r3.w);
  float* mp = mid + (size_t)bc*1024 + (gy*2)*32 + gx*2;
  *(float2*)mp        = make_float2(m00, m01);
  *(float2*)(mp + 32) = make_float2(m10, m11);
  glb[(size_t)bc*256 + gy*16 + gx] = 0.25f*(m00 + m01 + m10 + m11);
}

// ---------------- one-time: both weight transposes in one dispatch ----------------
__global__ __launch_bounds__(256) void transpose_ws(
    const float* __restrict__ Wqkv, const float* __restrict__ Wout,
    __bf16* __restrict__ WT, __bf16* __restrict__ WoT)
{
  __shared__ float T[64][68];
  int bx = blockIdx.x;
  const float* W; __bf16* D; int ncols, n0;
  if (bx < 12) { W = Wqkv; D = WT;  ncols = 768; n0 = bx*64; }
  else         { W = Wout; D = WoT; ncols = 256; n0 = (bx-12)*64; }
  int k0 = blockIdx.y*64;
  int tid = threadIdx.x;
  int c4 = (tid & 15)*4, rr = tid >> 4;
  #pragma unroll
  for (int p = 0; p < 4; ++p) {
    int row = p*16 + rr;
    float4 v = *(const float4*)(W + (size_t)(k0+row)*ncols + n0 + c4);
    T[c4+0][row] = v.x; T[c4+1][row] = v.y; T[c4+2][row] = v.z; T[c4+3][row] = v.w;
  }
  __syncthreads();
  #pragma unroll
  for (int p = 0; p < 4; ++p) {
    int cc = p*16 + rr;
    bf16x4 o;
    o[0] = (__bf16)T[cc][c4+0]; o[1] = (__bf16)T[cc][c4+1];
    o[2] = (__bf16)T[cc][c4+2]; o[3] = (__bf16)T[cc][c4+3];
    *(bf16x4*)(D + (size_t)(n0+cc)*256 + k0 + c4) = o;
  }
}

// ---------------- pooled tokens: transpose [c][tok] fp32 -> [tok][c] bf16 ----------------
__global__ __launch_bounds__(256) void transpose_tok(
    const float* __restrict__ mid, const float* __restrict__ glb,
    __bf16* __restrict__ mgt)
{
  __shared__ float T[64][68];
  int t0 = blockIdx.x*64, c0 = blockIdx.y*64, b = blockIdx.z;
  const float* src; int stride, toff;
  if (t0 < 1024) { src = mid + ((size_t)(b*256 + c0))*1024; stride = 1024; toff = t0; }
  else           { src = glb + ((size_t)(b*256 + c0))*256;  stride = 256;  toff = t0 - 1024; }
  int tid = threadIdx.x;
  int c4 = (tid & 15)*4, rr = tid >> 4;
  #pragma unroll
  for (int p = 0; p < 4; ++p) {
    int row = p*16 + rr;                 // channel offset
    float4 v = *(const float4*)(src + (size_t)row*stride + toff + c4);
    T[c4+0][row] = v.x; T[c4+1][row] = v.y; T[c4+2][row] = v.z; T[c4+3][row] = v.w;
  }
  __syncthreads();
  #pragma unroll
  for (int p = 0; p < 4; ++p) {
    int tt = p*16 + rr;                  // token offset
    bf16x4 o;
    o[0] = (__bf16)T[tt][c4+0]; o[1] = (__bf16)T[tt][c4+1];
    o[2] = (__bf16)T[tt][c4+2]; o[3] = (__bf16)T[tt][c4+3];
    *(bf16x4*)(mgt + ((size_t)b*1280 + t0 + tt)*256 + c0 + c4) = o;
  }
}

// ---------------- q GEMM (MFMA, swapped operands); scale includes log2(e) ----------------
__global__ __launch_bounds__(256) void gemm_q_mfma(
    const __bf16* __restrict__ qnb, const __bf16* __restrict__ WT,
    const float* __restrict__ qkvb, __bf16* __restrict__ qbf)
{
  int tid = threadIdx.x, wv = tid >> 6, lane = tid & 63;
  int col = lane & 15, quad = lane >> 4;
  int win = blockIdx.x*2 + (wv >> 1);
  int nbase = (wv & 1)*8;
  bf16x8 bq[8];
  const __bf16* qp = qnb + ((size_t)win*16 + col)*256 + quad*8;
  #pragma unroll
  for (int kk = 0; kk < 8; ++kk) bq[kk] = *(const bf16x8*)(qp + kk*32);
  const f32x4 zero = {0.f,0.f,0.f,0.f};
  #pragma unroll
  for (int nt = 0; nt < 8; ++nt) {
    int n0 = (nbase+nt)*16;
    const __bf16* wp = WT + ((size_t)(n0+col))*256 + quad*8;
    f32x4 acc = zero;
    #pragma unroll
    for (int kk = 0; kk < 8; ++kk) {
      bf16x8 wf = *(const bf16x8*)(wp + kk*32);
      acc = __builtin_amdgcn_mfma_f32_16x16x32_bf16(wf, bq[kk], acc, 0, 0, 0);
    }
    float4 b4 = *(const float4*)(qkvb + n0 + quad*4);
    float bb[4] = {b4.x,b4.y,b4.z,b4.w};
    bf16x4 o;
    #pragma unroll
    for (int r = 0; r < 4; ++r) o[r] = (__bf16)((acc[r]+bb[r])*QSCALE_L2E);
    *(bf16x4*)(qbf + ((size_t)win*16 + col)*256 + n0 + quad*4) = o;
  }
}

// ---------------- local KV v3: block = 2 windows, B-tile shared across both ----------------
// Each staged 32-row WT tile feeds 2 windows x 64 tokens (vs 64 tokens in r8):
// halves LDS B-read instructions per FLOP and halves barrier count (16 vs 32).
// A-frags for both windows cached in VGPRs (64 regs); grid 256 = 1 block/CU.
__global__ __launch_bounds__(256) void loc_kv_mfma(
    const float* __restrict__ F, const __bf16* __restrict__ WT,
    const float* __restrict__ qkvb,
    __bf16* __restrict__ kloc, __bf16* __restrict__ vloct)
{
  __shared__ __bf16 As[2*64*264];      // 66 KB: two windows' im2col A
  __shared__ __bf16 Bs[2*32*264];      // 33 KB: double-buffered 32-row WT tiles
  int blk = blockIdx.x;                // b*128 + window-pair
  int b = blk >> 7, pr = blk & 127;
  int w0 = pr*2;
  int bw0 = b*256 + w0;
  int tid = threadIdx.x;

  // ---- im2col gather, both windows ----
  #pragma unroll
  for (int wi = 0; wi < 2; ++wi) {
    int w = w0 + wi;
    int wy4 = ((w >> 4) << 2) - 2, wx4 = ((w & 15) << 2) - 2;
    int xp = tid & 3;
    int dy = (tid >> 2) & 7;
    int cg = tid >> 5;
    int yy = wy4 + dy, xx = wx4 + xp*2;
    bool inb = ((unsigned)yy < 64u) && ((unsigned)xx < 64u);
    const float* Fp = F + ((size_t)b*256)*HWSZ + yy*64 + xx;
    __bf16* Aw = As + wi*16896;
    #pragma unroll 4
    for (int i = 0; i < 32; ++i) {
      int ch = cg*32 + i;
      float2 v = make_float2(0.f, 0.f);
      if (inb) v = *(const float2*)(Fp + (size_t)ch*HWSZ);
      int t = ch >> 2, r = ch & 3;
      bf16x2 o; o[0] = (__bf16)v.x; o[1] = (__bf16)v.y;
      *(bf16x2*)&Aw[t*264 + r*64 + dy*8 + xp*2] = o;
    }
  }

  // ---- B staging assignment: thread -> 64 B of one of 32 rows ----
  int brow = tid >> 3, bc0 = (tid & 7)*32;   // row 0..31, elem offset 0..224
  const __bf16* wsrc = WT + ((size_t)(256 + brow))*256 + bc0;
  __bf16* bdst = Bs + brow*264 + bc0;

  // prologue: tile 0 -> Bs[0]; prefetch tile 1 into regs
  bf16x8 g[4];
  {
    bf16x8 a0 = *(const bf16x8*)(wsrc);
    bf16x8 a1 = *(const bf16x8*)(wsrc + 8);
    bf16x8 a2 = *(const bf16x8*)(wsrc + 16);
    bf16x8 a3 = *(const bf16x8*)(wsrc + 24);
    *(bf16x8*)(bdst)      = a0;
    *(bf16x8*)(bdst + 8)  = a1;
    *(bf16x8*)(bdst + 16) = a2;
    *(bf16x8*)(bdst + 24) = a3;
  }
  #pragma unroll
  for (int j = 0; j < 4; ++j) g[j] = *(const bf16x8*)(wsrc + (size_t)1*8192 + j*8);
  __syncthreads();   // As (both windows) + Bs tile0 ready

  int wv = tid >> 6, lane = tid & 63;
  int col = lane & 15, quad = lane >> 4;
  int m0 = wv*16;                      // this wave's m-tile (same for both windows)
  bf16x8 af[2][8];
  #pragma unroll
  for (int wi = 0; wi < 2; ++wi)
    #pragma unroll
    for (int kk = 0; kk < 8; ++kk)
      af[wi][kk] = *(const bf16x8*)&As[wi*16896 + (m0+col)*264 + kk*32 + quad*8];

  const f32x4 zero = {0.f,0.f,0.f,0.f};
  #pragma unroll 1
  for (int s = 0; s < 16; ++s) {       // 16 steps x 32 cols
    __bf16* Bbuf = Bs + (s & 1)*8448;
    // write tile s+1 (in regs) to the other buffer; prefetch tile s+2
    if (s < 15) {
      __bf16* d = Bs + ((s+1) & 1)*8448 + brow*264 + bc0;
      *(bf16x8*)(d)      = g[0];
      *(bf16x8*)(d + 8)  = g[1];
      *(bf16x8*)(d + 16) = g[2];
      *(bf16x8*)(d + 24) = g[3];
    }
    if (s < 14) {
      const __bf16* p = wsrc + (size_t)(s+2)*8192;
      #pragma unroll
      for (int j = 0; j < 4; ++j) g[j] = *(const bf16x8*)(p + j*8);
    }
    #pragma unroll
    for (int nt2 = 0; nt2 < 2; ++nt2) {
      int n = s*32 + nt2*16 + col;     // 0..511
      float bias_n = qkvb[256 + n];
      const __bf16* Bb = Bbuf + (nt2*16 + col)*264 + quad*8;
      f32x4 acc0 = zero, acc1 = zero;
      #pragma unroll
      for (int kk = 0; kk < 8; ++kk) {
        bf16x8 bv = *(const bf16x8*)(Bb + kk*32);
        acc0 = __builtin_amdgcn_mfma_f32_16x16x32_bf16(af[0][kk], bv, acc0, 0, 0, 0);
        acc1 = __builtin_amdgcn_mfma_f32_16x16x32_bf16(af[1][kk], bv, acc1, 0, 0, 0);
      }
      if (n < 256) {
        #pragma unroll
        for (int r = 0; r < 4; ++r) {
          kloc[((size_t)bw0*64       + m0 + quad*4 + r)*256 + n] = (__bf16)(acc0[r] + bias_n);
          kloc[((size_t)(bw0+1)*64   + m0 + quad*4 + r)*256 + n] = (__bf16)(acc1[r] + bias_n);
        }
      } else {
        bf16x4 o0, o1;
        #pragma unroll
        for (int r = 0; r < 4; ++r) {
          o0[r] = (__bf16)(acc0[r] + bias_n);
          o1[r] = (__bf16)(acc1[r] + bias_n);
        }
        *(bf16x4*)(vloct + ((size_t)bw0*256     + (n - 256))*64 + m0 + quad*4) = o0;
        *(bf16x4*)(vloct + ((size_t)(bw0+1)*256 + (n - 256))*64 + m0 + quad*4) = o1;
      }
    }
    __syncthreads();
  }
}

// ---------------- mid/glb KV: MFMA over token-major mgt ----------------
__global__ __launch_bounds__(256) void mg_kv_mfma(
    const __bf16* __restrict__ mgt, const __bf16* __restrict__ WT,
    const float* __restrict__ qkvb,
    __bf16* __restrict__ kmg, __bf16* __restrict__ vmgt)
{
  int tb = blockIdx.x, nq = blockIdx.y, b = blockIdx.z;
  int tid = threadIdx.x, wv = tid >> 6, lane = tid & 63;
  int col = lane & 15, quad = lane >> 4;
  int m0 = tb*64 + wv*16;
  const __bf16* Ab = mgt + ((size_t)b*1280 + m0 + col)*256 + quad*8;
  bf16x8 af[8];
  #pragma unroll
  for (int kk = 0; kk < 8; ++kk) af[kk] = *(const bf16x8*)(Ab + kk*32);
  const f32x4 zero = {0.f,0.f,0.f,0.f};
  #pragma unroll 2
  for (int nt = nq*8; nt < nq*8 + 8; ++nt) {
    int n = nt*16 + col;                  // 0..511
    float bias_n = qkvb[256 + n];
    const __bf16* Wp = WT + (size_t)(256 + n)*256 + quad*8;
    f32x4 acc = zero;
    #pragma unroll
    for (int kk = 0; kk < 8; ++kk) {
      bf16x8 bv = *(const bf16x8*)(Wp + kk*32);
      acc = __builtin_amdgcn_mfma_f32_16x16x32_bf16(af[kk], bv, acc, 0, 0, 0);
    }
    if (nt < 16) {
      #pragma unroll
      for (int r = 0; r < 4; ++r)
        kmg[((size_t)b*1280 + m0 + quad*4 + r)*256 + n] = (__bf16)(acc[r] + bias_n);
    } else {
      bf16x4 o;
      #pragma unroll
      for (int r = 0; r < 4; ++r) o[r] = (__bf16)(acc[r] + bias_n);
      *(bf16x4*)(vmgt + ((size_t)b*256 + (n - 256))*1280 + m0 + quad*4) = o;
    }
  }
}

// ---------------- MFMA fused attention (r8 version: LDS K/V staging, 8 waves) ----------------
__global__ __launch_bounds__(512) void attn_mfma(
    const __bf16* __restrict__ qbf, const __bf16* __restrict__ kloc,
    const __bf16* __restrict__ vloct, const __bf16* __restrict__ kmg,
    const __bf16* __restrict__ vmgt, __bf16* __restrict__ obf)
{
  __shared__ __bf16 Ks[3][32][40];
  __shared__ __bf16 Vs[3][32][40];
  __shared__ __bf16 Pb[8][2][16][40];
  int blk = blockIdx.x;
  int b = blk >> 8, rr = blk & 255;
  int h = rr >> 5, wg = rr & 31;
  int tid = threadIdx.x, wv = tid >> 6, lane = tid & 63;
  int col = lane & 15, quad = lane >> 4;
  int bw = b*256 + wg*8 + wv;           // this wave's window

  int r64 = tid >> 3, l8 = tid & 7;
  bool isK = r64 < 32;
  int srow = isK ? r64 : r64 - 32;
  const __bf16* gbase = isK
      ? kmg  + ((size_t)(b*1280 + srow))*256 + h*32 + l8*4
      : vmgt + ((size_t)(b*256 + h*32 + srow))*1280 + l8*4;
  size_t gstride = isK ? 256 : 1;
  __bf16* lbase = isK ? &Ks[0][srow][l8*4] : &Vs[0][srow][l8*4];

  bf16x8 aq = *(const bf16x8*)(qbf + ((size_t)(bw*16 + col))*256 + h*32 + quad*8);
  f32x4 O0 = {0.f,0.f,0.f,0.f}, O1 = {0.f,0.f,0.f,0.f};
  const f32x4 zero = {0.f,0.f,0.f,0.f};
  float ls[4] = {0.f,0.f,0.f,0.f};
  __bf16* PwBase = &Pb[wv][0][0][0];

  bf16x4 sreg = *(const bf16x4*)gbase;

  const __bf16* klocb = kloc  + (size_t)bw*16384 + h*32 + quad*8;
  const __bf16* vlocb = vloct + (size_t)bw*16384 + (size_t)(h*32)*64 + quad*8;
  #pragma unroll
  for (int ch = 0; ch < 2; ++ch) {
    bf16x8 k0 = *(const bf16x8*)(klocb + (size_t)(ch*32 + col)*256);
    bf16x8 k1 = *(const bf16x8*)(klocb + (size_t)(ch*32 + 16 + col)*256);
    bf16x8 v0 = *(const bf16x8*)(vlocb + (size_t)col*64 + ch*32);
    bf16x8 v1 = *(const bf16x8*)(vlocb + (size_t)(16+col)*64 + ch*32);
    f32x4 S0 = __builtin_amdgcn_mfma_f32_16x16x32_bf16(aq, k0, zero, 0, 0, 0);
    f32x4 S1 = __builtin_amdgcn_mfma_f32_16x16x32_bf16(aq, k1, zero, 0, 0, 0);
    __bf16* Pw = PwBase + (ch & 1)*640;
    #pragma unroll
    for (int r = 0; r < 4; ++r) {
      float p0 = __builtin_amdgcn_exp2f(S0[r]);
      float p1 = __builtin_amdgcn_exp2f(S1[r]);
      ls[r] += p0 + p1;
      Pw[(quad*4+r)*40 + col]      = (__bf16)p0;
      Pw[(quad*4+r)*40 + 16 + col] = (__bf16)p1;
    }
    bf16x8 ap = *(const bf16x8*)(Pw + (size_t)col*40 + quad*8);
    O0 = __builtin_amdgcn_mfma_f32_16x16x32_bf16(ap, v0, O0, 0, 0, 0);
    O1 = __builtin_amdgcn_mfma_f32_16x16x32_bf16(ap, v1, O1, 0, 0, 0);
  }

  *(bf16x4*)(lbase + 2*1280) = sreg;
  sreg = *(const bf16x4*)(gbase + (size_t)32*gstride);
  __syncthreads();

  int buf = 2;
  #pragma unroll 1
  for (int ch = 2; ch < 42; ++ch) {
    int nbuf = (buf == 2) ? 0 : buf + 1;
    if (ch + 1 < 42) {
      *(bf16x4*)(lbase + nbuf*1280) = sreg;
      if (ch + 2 < 42)
        sreg = *(const bf16x4*)(gbase + (size_t)(ch*32)*gstride);
    }
    const __bf16* Kb = &Ks[buf][0][0];
    const __bf16* Vb = &Vs[buf][0][0];
    bf16x8 k0 = *(const bf16x8*)(Kb + col*40 + quad*8);
    bf16x8 k1 = *(const bf16x8*)(Kb + (16+col)*40 + quad*8);
    bf16x8 v0 = *(const bf16x8*)(Vb + col*40 + quad*8);
    bf16x8 v1 = *(const bf16x8*)(Vb + (16+col)*40 + quad*8);
    f32x4 S0 = __builtin_amdgcn_mfma_f32_16x16x32_bf16(aq, k0, zero, 0, 0, 0);
    f32x4 S1 = __builtin_amdgcn_mfma_f32_16x16x32_bf16(aq, k1, zero, 0, 0, 0);
    __bf16* Pw = PwBase + (ch & 1)*640;
    #pragma unroll
    for (int r = 0; r < 4; ++r) {
      float p0 = __builtin_amdgcn_exp2f(S0[r]);
      float p1 = __builtin_amdgcn_exp2f(S1[r]);
      ls[r] += p0 + p1;
      Pw[(quad*4+r)*40 + col]      = (__bf16)p0;
      Pw[(quad*4+r)*40 + 16 + col] = (__bf16)p1;
    }
    bf16x8 ap = *(const bf16x8*)(Pw + (size_t)col*40 + quad*8);
    O0 = __builtin_amdgcn_mfma_f32_16x16x32_bf16(ap, v0, O0, 0, 0, 0);
    O1 = __builtin_amdgcn_mfma_f32_16x16x32_bf16(ap, v1, O1, 0, 0, 0);
    buf = nbuf;
    __syncthreads();
  }

  #pragma unroll
  for (int r = 0; r < 4; ++r) {
    #pragma unroll
    for (int m = 1; m < 16; m <<= 1) ls[r] += __shfl_xor(ls[r], m);
  }
  __bf16* op = obf + ((size_t)(bw*16) + quad*4)*256 + h*32 + col;
  #pragma unroll
  for (int r = 0; r < 4; ++r) {
    float inv = 1.f / ls[r];
    op[(size_t)r*256]      = (__bf16)(O0[r]*inv);
    op[(size_t)r*256 + 16] = (__bf16)(O1[r]*inv);
  }
}

// ---------------- out projection, strip version ----------------
__global__ __launch_bounds__(256) void gemm_out_strip(
    const __bf16* __restrict__ obf, const __bf16* __restrict__ WoT,
    const float* __restrict__ outb, const float* __restrict__ Fres,
    float* __restrict__ Out)
{
  __shared__ __bf16 strip[64*264];     // [c64] stride 264, [py] stride 66, [x64]
  int blk = blockIdx.x;                // b*64 + wy*4 + cq
  int b = blk >> 6, wy = (blk >> 2) & 15, cq = blk & 3;
  int c0 = cq*64;
  int tid = threadIdx.x, wv = tid >> 6, lane = tid & 63;
  int col = lane & 15, quad = lane >> 4;
  const f32x4 zero = {0.f,0.f,0.f,0.f};

  #pragma unroll
  for (int i = 0; i < 4; ++i) {
    int wx = wv*4 + i;
    int win = b*256 + wy*16 + wx;
    bf16x8 ao[8];
    const __bf16* op = obf + ((size_t)win*16 + col)*256 + quad*8;
    #pragma unroll
    for (int kk = 0; kk < 8; ++kk) ao[kk] = *(const bf16x8*)(op + kk*32);
    #pragma unroll
    for (int nt = 0; nt < 4; ++nt) {
      int n = c0 + nt*16 + col;
      const __bf16* wp = WoT + ((size_t)n)*256 + quad*8;
      f32x4 acc = zero;
      #pragma unroll
      for (int kk = 0; kk < 8; ++kk) {
        bf16x8 wf = *(const bf16x8*)(wp + kk*32);
        acc = __builtin_amdgcn_mfma_f32_16x16x32_bf16(ao[kk], wf, acc, 0, 0, 0);
      }
      bf16x4 o;
      #pragma unroll
      for (int r = 0; r < 4; ++r) o[r] = (__bf16)acc[r];
      *(bf16x4*)&strip[(nt*16+col)*264 + quad*66 + wx*4] = o;
    }
  }
  __syncthreads();
  #pragma unroll
  for (int j = 0; j < 16; ++j) {
    int f4 = j*256 + tid;               // [c][y][xq]
    int xq = f4 & 15, y = (f4 >> 4) & 3, c = f4 >> 6;
    bf16x4 d = *(const bf16x4*)&strip[c*264 + y*66 + xq*4];
    size_t off = ((size_t)(b*256 + c0 + c))*HWSZ + (wy*4 + y)*64 + xq*4;
    float4 r4 = *(const float4*)(Fres + off);
    float bn = outb[c0 + c];
    float4 o;
    o.x = (float)d[0] + bn + r4.x; o.y = (float)d[1] + bn + r4.y;
    o.z = (float)d[2] + bn + r4.z; o.w = (float)d[3] + bn + r4.w;
    *(float4*)(Out + off) = o;
  }
}

extern "C" void kernel_launch(void* const* d_in, const int* in_sizes, int n_in,
                              void* d_out, int out_size, void* d_ws, size_t ws_size,
                              hipStream_t stream) {
  const float* F     = (const float*)d_in[0];
  const float* qkv_w = (const float*)d_in[1];
  const float* qkv_b = (const float*)d_in[2];
  const float* out_w = (const float*)d_in[3];
  const float* out_b = (const float*)d_in[4];
  const float* ln_w  = (const float*)d_in[5];
  const float* ln_b  = (const float*)d_in[6];
  float* out = (float*)d_out;

  __bf16* qnb   = (__bf16*)d_ws;             // 2,097,152 h
  __bf16* qbf   = qnb   + 2097152;           // 2,097,152 h
  __bf16* obf   = qbf   + 2097152;           // 2,097,152 h
  __bf16* kloc  = obf   + 2097152;           // 8,388,608 h
  __bf16* vloct = kloc  + 8388608;           // 8,388,608 h
  __bf16* kmg   = vloct + 8388608;           // 655,360 h
  __bf16* vmgt  = kmg   + 655360;            // 655,360 h
  __bf16* mgt   = vmgt  + 655360;            // 655,360 h
  __bf16* WT    = mgt   + 655360;            // 196,608 h
  __bf16* WoT   = WT    + 196608;            // 65,536 h
  float*  mid   = (float*)(WoT + 65536);     // 524,288 f
  float*  glb   = mid   + 524288;            // 131,072 f

  transpose_ws<<<dim3(16, 4), 256, 0, stream>>>(qkv_w, out_w, WT, WoT);
  ln_qn_kernel<<<512, 256, 0, stream>>>(F, ln_w, ln_b, qnb);
  pool_kernel<<<512, 256, 0, stream>>>(F, mid, glb);
  transpose_tok<<<dim3(20, 4, 2), 256, 0, stream>>>(mid, glb, mgt);
  gemm_q_mfma<<<256, 256, 0, stream>>>(qnb, WT, qkv_b, qbf);
  loc_kv_mfma<<<256, 256, 0, stream>>>(F, WT, qkv_b, kloc, vloct);
  mg_kv_mfma<<<dim3(20, 4, 2), 256, 0, stream>>>(mgt, WT, qkv_b, kmg, vmgt);
  attn_mfma<<<512, 512, 0, stream>>>(qbf, kloc, vloct, kmg, vmgt, obf);
  gemm_out_strip<<<128, 256, 0, stream>>>(obf, WoT, out_b, F, out);
}

// Round 11
// 194.365 us; speedup vs baseline: 1.0608x; 1.0608x over previous
//
#include <hip/hip_runtime.h>
#include <math.h>

#define HWSZ 4096   // 64*64
// 1/sqrt(32) * log2(e): scores come out pre-multiplied by log2(e), so softmax
// uses p = exp2(S) (single v_exp_f32) -- mathematically identical.
#define QSCALE_L2E 0.25501988932587245f

typedef __bf16 bf16x2 __attribute__((ext_vector_type(2)));
typedef __bf16 bf16x4 __attribute__((ext_vector_type(4)));
typedef __bf16 bf16x8 __attribute__((ext_vector_type(8)));
typedef float  f32x4  __attribute__((ext_vector_type(4)));

// ---------------- scrambled-token LayerNorm, strip version ----------------
__global__ __launch_bounds__(256) void ln_qn_kernel(
    const float* __restrict__ F, const float* __restrict__ lnw,
    const float* __restrict__ lnb, __bf16* __restrict__ qnb)
{
  __shared__ float sm[16*269];         // [c16] stride 269, [py] stride 67, [x]
  int blk = blockIdx.x;                // b*256 + wy*16 + t
  int b = blk >> 8, wy = (blk >> 4) & 15, t = blk & 15;
  int tid = threadIdx.x;
  const float* Fb = F + ((size_t)(b*256 + t*16))*HWSZ + (wy*4)*64;
  int py = tid >> 6, x = tid & 63;
  #pragma unroll
  for (int j = 0; j < 16; ++j)
    sm[j*269 + py*67 + x] = Fb[(size_t)j*HWSZ + py*64 + x];
  __syncthreads();
  int wx = tid >> 4, cl = tid & 15;    // window wx, channel-lane cl
  float vals[16], s1 = 0.f, s2 = 0.f;
  #pragma unroll
  for (int p = 0; p < 16; ++p) {
    float v = sm[cl*269 + (p >> 2)*67 + wx*4 + (p & 3)];
    vals[p] = v; s1 += v; s2 += v*v;
  }
  #pragma unroll
  for (int m = 1; m < 16; m <<= 1) { s1 += __shfl_xor(s1, m); s2 += __shfl_xor(s2, m); }
  float mean = s1 * (1.f/256.f);
  float var  = s2 * (1.f/256.f) - mean*mean;
  float rstd = rsqrtf(var + 1e-5f);
  __bf16* outp = qnb + (((size_t)(b*256 + wy*16 + wx))*16 + t)*256 + cl*16;
  bf16x8 o0, o1;
  #pragma unroll
  for (int p = 0; p < 8; ++p) {
    o0[p] = (__bf16)((vals[p]  -mean)*rstd*lnw[cl*16+p]   + lnb[cl*16+p]);
    o1[p] = (__bf16)((vals[p+8]-mean)*rstd*lnw[cl*16+p+8] + lnb[cl*16+p+8]);
  }
  *(bf16x8*)outp = o0;
  *(bf16x8*)(outp+8) = o1;
}

// ---------------- fused pools: thread = 2x2 mid patch -> 1 glb elem ----------------
__global__ __launch_bounds__(256) void pool_kernel(
    const float* __restrict__ F, float* __restrict__ mid, float* __restrict__ glb)
{
  int bc = blockIdx.x;                  // b*256 + c
  int t = threadIdx.x;
  int gy = t >> 4, gx = t & 15;
  const float* p = F + (size_t)bc*HWSZ + (gy*4)*64 + gx*4;
  float4 r0 = *(const float4*)(p);
  float4 r1 = *(const float4*)(p + 64);
  float4 r2 = *(const float4*)(p + 128);
  float4 r3 = *(const float4*)(p + 192);
  float m00 = 0.25f*(r0.x + r0.y + r1.x + r1.y);
  float m01 = 0.25f*(r0.z + r0.w + r1.z + r1.w);
  float m10 = 0.25f*(r2.x + r2.y + r3.x + r3.y);
  float m11 = 0.25f*(r2.z + r2.w + r3.z + r3.w);
  float* mp = mid + (size_t)bc*1024 + (gy*2)*32 + gx*2;
  *(float2*)mp        = make_float2(m00, m01);
  *(float2*)(mp + 32) = make_float2(m10, m11);
  glb[(size_t)bc*256 + gy*16 + gx] = 0.25f*(m00 + m01 + m10 + m11);
}

// ---------------- one-time: both weight transposes in one dispatch ----------------
__global__ __launch_bounds__(256) void transpose_ws(
    const float* __restrict__ Wqkv, const float* __restrict__ Wout,
    __bf16* __restrict__ WT, __bf16* __restrict__ WoT)
{
  __shared__ float T[64][68];
  int bx = blockIdx.x;
  const float* W; __bf16* D; int ncols, n0;
  if (bx < 12) { W = Wqkv; D = WT;  ncols = 768; n0 = bx*64; }
  else         { W = Wout; D = WoT; ncols = 256; n0 = (bx-12)*64; }
  int k0 = blockIdx.y*64;
  int tid = threadIdx.x;
  int c4 = (tid & 15)*4, rr = tid >> 4;
  #pragma unroll
  for (int p = 0; p < 4; ++p) {
    int row = p*16 + rr;
    float4 v = *(const float4*)(W + (size_t)(k0+row)*ncols + n0 + c4);
    T[c4+0][row] = v.x; T[c4+1][row] = v.y; T[c4+2][row] = v.z; T[c4+3][row] = v.w;
  }
  __syncthreads();
  #pragma unroll
  for (int p = 0; p < 4; ++p) {
    int cc = p*16 + rr;
    bf16x4 o;
    o[0] = (__bf16)T[cc][c4+0]; o[1] = (__bf16)T[cc][c4+1];
    o[2] = (__bf16)T[cc][c4+2]; o[3] = (__bf16)T[cc][c4+3];
    *(bf16x4*)(D + (size_t)(n0+cc)*256 + k0 + c4) = o;
  }
}

// ---------------- pooled tokens: transpose [c][tok] fp32 -> [tok][c] bf16 ----------------
__global__ __launch_bounds__(256) void transpose_tok(
    const float* __restrict__ mid, const float* __restrict__ glb,
    __bf16* __restrict__ mgt)
{
  __shared__ float T[64][68];
  int t0 = blockIdx.x*64, c0 = blockIdx.y*64, b = blockIdx.z;
  const float* src; int stride, toff;
  if (t0 < 1024) { src = mid + ((size_t)(b*256 + c0))*1024; stride = 1024; toff = t0; }
  else           { src = glb + ((size_t)(b*256 + c0))*256;  stride = 256;  toff = t0 - 1024; }
  int tid = threadIdx.x;
  int c4 = (tid & 15)*4, rr = tid >> 4;
  #pragma unroll
  for (int p = 0; p < 4; ++p) {
    int row = p*16 + rr;                 // channel offset
    float4 v = *(const float4*)(src + (size_t)row*stride + toff + c4);
    T[c4+0][row] = v.x; T[c4+1][row] = v.y; T[c4+2][row] = v.z; T[c4+3][row] = v.w;
  }
  __syncthreads();
  #pragma unroll
  for (int p = 0; p < 4; ++p) {
    int tt = p*16 + rr;                  // token offset
    bf16x4 o;
    o[0] = (__bf16)T[tt][c4+0]; o[1] = (__bf16)T[tt][c4+1];
    o[2] = (__bf16)T[tt][c4+2]; o[3] = (__bf16)T[tt][c4+3];
    *(bf16x4*)(mgt + ((size_t)b*1280 + t0 + tt)*256 + c0 + c4) = o;
  }
}

// ---------------- q GEMM (MFMA, swapped operands); scale includes log2(e) ----------------
__global__ __launch_bounds__(256) void gemm_q_mfma(
    const __bf16* __restrict__ qnb, const __bf16* __restrict__ WT,
    const float* __restrict__ qkvb, __bf16* __restrict__ qbf)
{
  int tid = threadIdx.x, wv = tid >> 6, lane = tid & 63;
  int col = lane & 15, quad = lane >> 4;
  int win = blockIdx.x*2 + (wv >> 1);
  int nbase = (wv & 1)*8;
  bf16x8 bq[8];
  const __bf16* qp = qnb + ((size_t)win*16 + col)*256 + quad*8;
  #pragma unroll
  for (int kk = 0; kk < 8; ++kk) bq[kk] = *(const bf16x8*)(qp + kk*32);
  const f32x4 zero = {0.f,0.f,0.f,0.f};
  #pragma unroll
  for (int nt = 0; nt < 8; ++nt) {
    int n0 = (nbase+nt)*16;
    const __bf16* wp = WT + ((size_t)(n0+col))*256 + quad*8;
    f32x4 acc = zero;
    #pragma unroll
    for (int kk = 0; kk < 8; ++kk) {
      bf16x8 wf = *(const bf16x8*)(wp + kk*32);
      acc = __builtin_amdgcn_mfma_f32_16x16x32_bf16(wf, bq[kk], acc, 0, 0, 0);
    }
    float4 b4 = *(const float4*)(qkvb + n0 + quad*4);
    float bb[4] = {b4.x,b4.y,b4.z,b4.w};
    bf16x4 o;
    #pragma unroll
    for (int r = 0; r < 4; ++r) o[r] = (__bf16)((acc[r]+bb[r])*QSCALE_L2E);
    *(bf16x4*)(qbf + ((size_t)win*16 + col)*256 + n0 + quad*4) = o;
  }
}

// ---------------- local KV v4: direct register A-frags, Bs-only LDS ----------------
// A-frag insight: c' = kk*32+quad*8+j -> r=kk>>1, dy=(kk&1)*4+quad, dx=j, so each
// lane's fragment is 8 CONTIGUOUS x-pixels of one F row: loaded straight from
// global (4 float2, boundary-predicated), once per wave. No As LDS, no gather
// stage -> LDS = 16.9 KB Bs double-buffer -> ~6 blocks/CU (vs 1-2 in r8/r10).
__global__ __launch_bounds__(256) void loc_kv_mfma(
    const float* __restrict__ F, const __bf16* __restrict__ WT,
    const float* __restrict__ qkvb,
    __bf16* __restrict__ kloc, __bf16* __restrict__ vloct)
{
  __shared__ __bf16 Bs[2][16*264];     // 16.5 KB
  int bw = blockIdx.x;
  int b = bw >> 8, w = bw & 255;
  int wy = w >> 4, wx = w & 15;
  int tid = threadIdx.x;
  int wv = tid >> 6, lane = tid & 63;
  int col = lane & 15, quad = lane >> 4;
  int m0 = wv*16;

  // ---- direct A-frag loads ----
  bf16x8 af[8];
  int x0 = wx*4 - 2;
  bool p0ok = (wx > 0), p3ok = (wx < 15);
  const float* Fb = F + ((size_t)(b*256 + 4*(m0+col)))*HWSZ;
  #pragma unroll
  for (int kk = 0; kk < 8; ++kk) {
    int r = kk >> 1;
    int y = wy*4 + (kk & 1)*4 + quad - 2;
    bool yok = ((unsigned)y < 64u);
    const float* row = Fb + (size_t)r*HWSZ + y*64 + x0;
    float2 v0 = make_float2(0.f,0.f), v1 = make_float2(0.f,0.f);
    float2 v2 = make_float2(0.f,0.f), v3 = make_float2(0.f,0.f);
    if (yok) {
      if (p0ok) v0 = *(const float2*)(row);
      v1 = *(const float2*)(row + 2);
      v2 = *(const float2*)(row + 4);
      if (p3ok) v3 = *(const float2*)(row + 6);
    }
    af[kk][0] = (__bf16)v0.x; af[kk][1] = (__bf16)v0.y;
    af[kk][2] = (__bf16)v1.x; af[kk][3] = (__bf16)v1.y;
    af[kk][4] = (__bf16)v2.x; af[kk][5] = (__bf16)v2.y;
    af[kk][6] = (__bf16)v3.x; af[kk][7] = (__bf16)v3.y;
  }

  // ---- B staging: thread -> 32 B of one of 16 rows; double buffer, dist-2 ----
  int brow = tid >> 4, bseg = tid & 15;
  const __bf16* wsrc = WT + ((size_t)(256 + brow))*256 + bseg*16;
  __bf16* bd0 = &Bs[0][0] + brow*264 + bseg*16;
  {
    bf16x8 a0 = *(const bf16x8*)wsrc;
    bf16x8 a1 = *(const bf16x8*)(wsrc + 8);
    *(bf16x8*)bd0 = a0;
    *(bf16x8*)(bd0 + 8) = a1;
  }
  bf16x8 g0 = *(const bf16x8*)(wsrc + (size_t)4096);
  bf16x8 g1 = *(const bf16x8*)(wsrc + (size_t)4096 + 8);
  __syncthreads();   // Bs[0] ready

  const f32x4 zero = {0.f,0.f,0.f,0.f};
  #pragma unroll 1
  for (int nt = 0; nt < 32; ++nt) {
    // write tile nt+1 (in regs) into the other buffer; prefetch tile nt+2
    if (nt < 31) {
      __bf16* d = &Bs[(nt+1) & 1][0] + brow*264 + bseg*16;
      *(bf16x8*)d = g0;
      *(bf16x8*)(d + 8) = g1;
    }
    if (nt < 30) {
      const __bf16* p = wsrc + (size_t)(nt+2)*4096;
      g0 = *(const bf16x8*)p;
      g1 = *(const bf16x8*)(p + 8);
    }
    int n = nt*16 + col;
    float bias_n = qkvb[256 + n];
    const __bf16* Bb = &Bs[nt & 1][0] + col*264 + quad*8;
    f32x4 acc = zero;
    #pragma unroll
    for (int kk = 0; kk < 8; ++kk) {
      bf16x8 bv = *(const bf16x8*)(Bb + kk*32);
      acc = __builtin_amdgcn_mfma_f32_16x16x32_bf16(af[kk], bv, acc, 0, 0, 0);
    }
    if (nt < 16) {
      #pragma unroll
      for (int r = 0; r < 4; ++r)
        kloc[((size_t)bw*64 + m0 + quad*4 + r)*256 + n] = (__bf16)(acc[r] + bias_n);
    } else {
      bf16x4 o;
      #pragma unroll
      for (int r = 0; r < 4; ++r) o[r] = (__bf16)(acc[r] + bias_n);
      *(bf16x4*)(vloct + ((size_t)bw*256 + (n - 256))*64 + m0 + quad*4) = o;
    }
    __syncthreads();
  }
}

// ---------------- mid/glb KV: MFMA over token-major mgt ----------------
__global__ __launch_bounds__(256) void mg_kv_mfma(
    const __bf16* __restrict__ mgt, const __bf16* __restrict__ WT,
    const float* __restrict__ qkvb,
    __bf16* __restrict__ kmg, __bf16* __restrict__ vmgt)
{
  int tb = blockIdx.x, nq = blockIdx.y, b = blockIdx.z;
  int tid = threadIdx.x, wv = tid >> 6, lane = tid & 63;
  int col = lane & 15, quad = lane >> 4;
  int m0 = tb*64 + wv*16;
  const __bf16* Ab = mgt + ((size_t)b*1280 + m0 + col)*256 + quad*8;
  bf16x8 af[8];
  #pragma unroll
  for (int kk = 0; kk < 8; ++kk) af[kk] = *(const bf16x8*)(Ab + kk*32);
  const f32x4 zero = {0.f,0.f,0.f,0.f};
  #pragma unroll 2
  for (int nt = nq*8; nt < nq*8 + 8; ++nt) {
    int n = nt*16 + col;                  // 0..511
    float bias_n = qkvb[256 + n];
    const __bf16* Wp = WT + (size_t)(256 + n)*256 + quad*8;
    f32x4 acc = zero;
    #pragma unroll
    for (int kk = 0; kk < 8; ++kk) {
      bf16x8 bv = *(const bf16x8*)(Wp + kk*32);
      acc = __builtin_amdgcn_mfma_f32_16x16x32_bf16(af[kk], bv, acc, 0, 0, 0);
    }
    if (nt < 16) {
      #pragma unroll
      for (int r = 0; r < 4; ++r)
        kmg[((size_t)b*1280 + m0 + quad*4 + r)*256 + n] = (__bf16)(acc[r] + bias_n);
    } else {
      bf16x4 o;
      #pragma unroll
      for (int r = 0; r < 4; ++r) o[r] = (__bf16)(acc[r] + bias_n);
      *(bf16x4*)(vmgt + ((size_t)b*256 + (n - 256))*1280 + m0 + quad*4) = o;
    }
  }
}

// ---------------- MFMA fused attention (r8 version: LDS K/V staging, 8 waves) ----------------
__global__ __launch_bounds__(512) void attn_mfma(
    const __bf16* __restrict__ qbf, const __bf16* __restrict__ kloc,
    const __bf16* __restrict__ vloct, const __bf16* __restrict__ kmg,
    const __bf16* __restrict__ vmgt, __bf16* __restrict__ obf)
{
  __shared__ __bf16 Ks[3][32][40];
  __shared__ __bf16 Vs[3][32][40];
  __shared__ __bf16 Pb[8][2][16][40];
  int blk = blockIdx.x;
  int b = blk >> 8, rr = blk & 255;
  int h = rr >> 5, wg = rr & 31;
  int tid = threadIdx.x, wv = tid >> 6, lane = tid & 63;
  int col = lane & 15, quad = lane >> 4;
  int bw = b*256 + wg*8 + wv;           // this wave's window

  int r64 = tid >> 3, l8 = tid & 7;
  bool isK = r64 < 32;
  int srow = isK ? r64 : r64 - 32;
  const __bf16* gbase = isK
      ? kmg  + ((size_t)(b*1280 + srow))*256 + h*32 + l8*4
      : vmgt + ((size_t)(b*256 + h*32 + srow))*1280 + l8*4;
  size_t gstride = isK ? 256 : 1;
  __bf16* lbase = isK ? &Ks[0][srow][l8*4] : &Vs[0][srow][l8*4];

  bf16x8 aq = *(const bf16x8*)(qbf + ((size_t)(bw*16 + col))*256 + h*32 + quad*8);
  f32x4 O0 = {0.f,0.f,0.f,0.f}, O1 = {0.f,0.f,0.f,0.f};
  const f32x4 zero = {0.f,0.f,0.f,0.f};
  float ls[4] = {0.f,0.f,0.f,0.f};
  __bf16* PwBase = &Pb[wv][0][0][0];

  bf16x4 sreg = *(const bf16x4*)gbase;

  const __bf16* klocb = kloc  + (size_t)bw*16384 + h*32 + quad*8;
  const __bf16* vlocb = vloct + (size_t)bw*16384 + (size_t)(h*32)*64 + quad*8;
  #pragma unroll
  for (int ch = 0; ch < 2; ++ch) {
    bf16x8 k0 = *(const bf16x8*)(klocb + (size_t)(ch*32 + col)*256);
    bf16x8 k1 = *(const bf16x8*)(klocb + (size_t)(ch*32 + 16 + col)*256);
    bf16x8 v0 = *(const bf16x8*)(vlocb + (size_t)col*64 + ch*32);
    bf16x8 v1 = *(const bf16x8*)(vlocb + (size_t)(16+col)*64 + ch*32);
    f32x4 S0 = __builtin_amdgcn_mfma_f32_16x16x32_bf16(aq, k0, zero, 0, 0, 0);
    f32x4 S1 = __builtin_amdgcn_mfma_f32_16x16x32_bf16(aq, k1, zero, 0, 0, 0);
    __bf16* Pw = PwBase + (ch & 1)*640;
    #pragma unroll
    for (int r = 0; r < 4; ++r) {
      float p0 = __builtin_amdgcn_exp2f(S0[r]);
      float p1 = __builtin_amdgcn_exp2f(S1[r]);
      ls[r] += p0 + p1;
      Pw[(quad*4+r)*40 + col]      = (__bf16)p0;
      Pw[(quad*4+r)*40 + 16 + col] = (__bf16)p1;
    }
    bf16x8 ap = *(const bf16x8*)(Pw + (size_t)col*40 + quad*8);
    O0 = __builtin_amdgcn_mfma_f32_16x16x32_bf16(ap, v0, O0, 0, 0, 0);
    O1 = __builtin_amdgcn_mfma_f32_16x16x32_bf16(ap, v1, O1, 0, 0, 0);
  }

  *(bf16x4*)(lbase + 2*1280) = sreg;
  sreg = *(const bf16x4*)(gbase + (size_t)32*gstride);
  __syncthreads();

  int buf = 2;
  #pragma unroll 1
  for (int ch = 2; ch < 42; ++ch) {
    int nbuf = (buf == 2) ? 0 : buf + 1;
    if (ch + 1 < 42) {
      *(bf16x4*)(lbase + nbuf*1280) = sreg;
      if (ch + 2 < 42)
        sreg = *(const bf16x4*)(gbase + (size_t)(ch*32)*gstride);
    }
    const __bf16* Kb = &Ks[buf][0][0];
    const __bf16* Vb = &Vs[buf][0][0];
    bf16x8 k0 = *(const bf16x8*)(Kb + col*40 + quad*8);
    bf16x8 k1 = *(const bf16x8*)(Kb + (16+col)*40 + quad*8);
    bf16x8 v0 = *(const bf16x8*)(Vb + col*40 + quad*8);
    bf16x8 v1 = *(const bf16x8*)(Vb + (16+col)*40 + quad*8);
    f32x4 S0 = __builtin_amdgcn_mfma_f32_16x16x32_bf16(aq, k0, zero, 0, 0, 0);
    f32x4 S1 = __builtin_amdgcn_mfma_f32_16x16x32_bf16(aq, k1, zero, 0, 0, 0);
    __bf16* Pw = PwBase + (ch & 1)*640;
    #pragma unroll
    for (int r = 0; r < 4; ++r) {
      float p0 = __builtin_amdgcn_exp2f(S0[r]);
      float p1 = __builtin_amdgcn_exp2f(S1[r]);
      ls[r] += p0 + p1;
      Pw[(quad*4+r)*40 + col]      = (__bf16)p0;
      Pw[(quad*4+r)*40 + 16 + col] = (__bf16)p1;
    }
    bf16x8 ap = *(const bf16x8*)(Pw + (size_t)col*40 + quad*8);
    O0 = __builtin_amdgcn_mfma_f32_16x16x32_bf16(ap, v0, O0, 0, 0, 0);
    O1 = __builtin_amdgcn_mfma_f32_16x16x32_bf16(ap, v1, O1, 0, 0, 0);
    buf = nbuf;
    __syncthreads();
  }

  #pragma unroll
  for (int r = 0; r < 4; ++r) {
    #pragma unroll
    for (int m = 1; m < 16; m <<= 1) ls[r] += __shfl_xor(ls[r], m);
  }
  __bf16* op = obf + ((size_t)(bw*16) + quad*4)*256 + h*32 + col;
  #pragma unroll
  for (int r = 0; r < 4; ++r) {
    float inv = 1.f / ls[r];
    op[(size_t)r*256]      = (__bf16)(O0[r]*inv);
    op[(size_t)r*256 + 16] = (__bf16)(O1[r]*inv);
  }
}

// ---------------- out projection, strip version ----------------
__global__ __launch_bounds__(256) void gemm_out_strip(
    const __bf16* __restrict__ obf, const __bf16* __restrict__ WoT,
    const float* __restrict__ outb, const float* __restrict__ Fres,
    float* __restrict__ Out)
{
  __shared__ __bf16 strip[64*264];     // [c64] stride 264, [py] stride 66, [x64]
  int blk = blockIdx.x;                // b*64 + wy*4 + cq
  int b = blk >> 6, wy = (blk >> 2) & 15, cq = blk & 3;
  int c0 = cq*64;
  int tid = threadIdx.x, wv = tid >> 6, lane = tid & 63;
  int col = lane & 15, quad = lane >> 4;
  const f32x4 zero = {0.f,0.f,0.f,0.f};

  #pragma unroll
  for (int i = 0; i < 4; ++i) {
    int wx = wv*4 + i;
    int win = b*256 + wy*16 + wx;
    bf16x8 ao[8];
    const __bf16* op = obf + ((size_t)win*16 + col)*256 + quad*8;
    #pragma unroll
    for (int kk = 0; kk < 8; ++kk) ao[kk] = *(const bf16x8*)(op + kk*32);
    #pragma unroll
    for (int nt = 0; nt < 4; ++nt) {
      int n = c0 + nt*16 + col;
      const __bf16* wp = WoT + ((size_t)n)*256 + quad*8;
      f32x4 acc = zero;
      #pragma unroll
      for (int kk = 0; kk < 8; ++kk) {
        bf16x8 wf = *(const bf16x8*)(wp + kk*32);
        acc = __builtin_amdgcn_mfma_f32_16x16x32_bf16(ao[kk], wf, acc, 0, 0, 0);
      }
      bf16x4 o;
      #pragma unroll
      for (int r = 0; r < 4; ++r) o[r] = (__bf16)acc[r];
      *(bf16x4*)&strip[(nt*16+col)*264 + quad*66 + wx*4] = o;
    }
  }
  __syncthreads();
  #pragma unroll
  for (int j = 0; j < 16; ++j) {
    int f4 = j*256 + tid;               // [c][y][xq]
    int xq = f4 & 15, y = (f4 >> 4) & 3, c = f4 >> 6;
    bf16x4 d = *(const bf16x4*)&strip[c*264 + y*66 + xq*4];
    size_t off = ((size_t)(b*256 + c0 + c))*HWSZ + (wy*4 + y)*64 + xq*4;
    float4 r4 = *(const float4*)(Fres + off);
    float bn = outb[c0 + c];
    float4 o;
    o.x = (float)d[0] + bn + r4.x; o.y = (float)d[1] + bn + r4.y;
    o.z = (float)d[2] + bn + r4.z; o.w = (float)d[3] + bn + r4.w;
    *(float4*)(Out + off) = o;
  }
}

extern "C" void kernel_launch(void* const* d_in, const int* in_sizes, int n_in,
                              void* d_out, int out_size, void* d_ws, size_t ws_size,
                              hipStream_t stream) {
  const float* F     = (const float*)d_in[0];
  const float* qkv_w = (const float*)d_in[1];
  const float* qkv_b = (const float*)d_in[2];
  const float* out_w = (const float*)d_in[3];
  const float* out_b = (const float*)d_in[4];
  const float* ln_w  = (const float*)d_in[5];
  const float* ln_b  = (const float*)d_in[6];
  float* out = (float*)d_out;

  __bf16* qnb   = (__bf16*)d_ws;             // 2,097,152 h
  __bf16* qbf   = qnb   + 2097152;           // 2,097,152 h
  __bf16* obf   = qbf   + 2097152;           // 2,097,152 h
  __bf16* kloc  = obf   + 2097152;           // 8,388,608 h
  __bf16* vloct = kloc  + 8388608;           // 8,388,608 h
  __bf16* kmg   = vloct + 8388608;           // 655,360 h
  __bf16* vmgt  = kmg   + 655360;            // 655,360 h
  __bf16* mgt   = vmgt  + 655360;            // 655,360 h
  __bf16* WT    = mgt   + 655360;            // 196,608 h
  __bf16* WoT   = WT    + 196608;            // 65,536 h
  float*  mid   = (float*)(WoT + 65536);     // 524,288 f
  float*  glb   = mid   + 524288;            // 131,072 f

  transpose_ws<<<dim3(16, 4), 256, 0, stream>>>(qkv_w, out_w, WT, WoT);
  ln_qn_kernel<<<512, 256, 0, stream>>>(F, ln_w, ln_b, qnb);
  pool_kernel<<<512, 256, 0, stream>>>(F, mid, glb);
  transpose_tok<<<dim3(20, 4, 2), 256, 0, stream>>>(mid, glb, mgt);
  gemm_q_mfma<<<256, 256, 0, stream>>>(qnb, WT, qkv_b, qbf);
  loc_kv_mfma<<<512, 256, 0, stream>>>(F, WT, qkv_b, kloc, vloct);
  mg_kv_mfma<<<dim3(20, 4, 2), 256, 0, stream>>>(mgt, WT, qkv_b, kmg, vmgt);
  attn_mfma<<<512, 512, 0, stream>>>(qbf, kloc, vloct, kmg, vmgt, obf);
  gemm_out_strip<<<128, 256, 0, stream>>>(obf, WoT, out_b, F, out);
}

// Round 12
// 167.962 us; speedup vs baseline: 1.2276x; 1.1572x over previous
//
#include <hip/hip_runtime.h>
#include <math.h>

#define HWSZ 4096   // 64*64
// 1/sqrt(32) * log2(e): scores come out pre-multiplied by log2(e), so softmax
// uses p = exp2(S) (single v_exp_f32) -- mathematically identical.
#define QSCALE_L2E 0.25501988932587245f

typedef __bf16 bf16x2 __attribute__((ext_vector_type(2)));
typedef __bf16 bf16x4 __attribute__((ext_vector_type(4)));
typedef __bf16 bf16x8 __attribute__((ext_vector_type(8)));
typedef float  f32x4  __attribute__((ext_vector_type(4)));

// ---------------- scrambled-token LayerNorm, strip version ----------------
__global__ __launch_bounds__(256) void ln_qn_kernel(
    const float* __restrict__ F, const float* __restrict__ lnw,
    const float* __restrict__ lnb, __bf16* __restrict__ qnb)
{
  __shared__ float sm[16*269];         // [c16] stride 269, [py] stride 67, [x]
  int blk = blockIdx.x;                // b*256 + wy*16 + t
  int b = blk >> 8, wy = (blk >> 4) & 15, t = blk & 15;
  int tid = threadIdx.x;
  const float* Fb = F + ((size_t)(b*256 + t*16))*HWSZ + (wy*4)*64;
  int py = tid >> 6, x = tid & 63;
  #pragma unroll
  for (int j = 0; j < 16; ++j)
    sm[j*269 + py*67 + x] = Fb[(size_t)j*HWSZ + py*64 + x];
  __syncthreads();
  int wx = tid >> 4, cl = tid & 15;    // window wx, channel-lane cl
  float vals[16], s1 = 0.f, s2 = 0.f;
  #pragma unroll
  for (int p = 0; p < 16; ++p) {
    float v = sm[cl*269 + (p >> 2)*67 + wx*4 + (p & 3)];
    vals[p] = v; s1 += v; s2 += v*v;
  }
  #pragma unroll
  for (int m = 1; m < 16; m <<= 1) { s1 += __shfl_xor(s1, m); s2 += __shfl_xor(s2, m); }
  float mean = s1 * (1.f/256.f);
  float var  = s2 * (1.f/256.f) - mean*mean;
  float rstd = rsqrtf(var + 1e-5f);
  __bf16* outp = qnb + (((size_t)(b*256 + wy*16 + wx))*16 + t)*256 + cl*16;
  bf16x8 o0, o1;
  #pragma unroll
  for (int p = 0; p < 8; ++p) {
    o0[p] = (__bf16)((vals[p]  -mean)*rstd*lnw[cl*16+p]   + lnb[cl*16+p]);
    o1[p] = (__bf16)((vals[p+8]-mean)*rstd*lnw[cl*16+p+8] + lnb[cl*16+p+8]);
  }
  *(bf16x8*)outp = o0;
  *(bf16x8*)(outp+8) = o1;
}

// ---------------- fused pools: thread = 2x2 mid patch -> 1 glb elem ----------------
__global__ __launch_bounds__(256) void pool_kernel(
    const float* __restrict__ F, float* __restrict__ mid, float* __restrict__ glb)
{
  int bc = blockIdx.x;                  // b*256 + c
  int t = threadIdx.x;
  int gy = t >> 4, gx = t & 15;
  const float* p = F + (size_t)bc*HWSZ + (gy*4)*64 + gx*4;
  float4 r0 = *(const float4*)(p);
  float4 r1 = *(const float4*)(p + 64);
  float4 r2 = *(const float4*)(p + 128);
  float4 r3 = *(const float4*)(p + 192);
  float m00 = 0.25f*(r0.x + r0.y + r1.x + r1.y);
  float m01 = 0.25f*(r0.z + r0.w + r1.z + r1.w);
  float m10 = 0.25f*(r2.x + r2.y + r3.x + r3.y);
  float m11 = 0.25f*(r2.z + r2.w + r3.z + r3.w);
  float* mp = mid + (size_t)bc*1024 + (gy*2)*32 + gx*2;
  *(float2*)mp        = make_float2(m00, m01);
  *(float2*)(mp + 32) = make_float2(m10, m11);
  glb[(size_t)bc*256 + gy*16 + gx] = 0.25f*(m00 + m01 + m10 + m11);
}

// ---------------- one-time: both weight transposes in one dispatch ----------------
__global__ __launch_bounds__(256) void transpose_ws(
    const float* __restrict__ Wqkv, const float* __restrict__ Wout,
    __bf16* __restrict__ WT, __bf16* __restrict__ WoT)
{
  __shared__ float T[64][68];
  int bx = blockIdx.x;
  const float* W; __bf16* D; int ncols, n0;
  if (bx < 12) { W = Wqkv; D = WT;  ncols = 768; n0 = bx*64; }
  else         { W = Wout; D = WoT; ncols = 256; n0 = (bx-12)*64; }
  int k0 = blockIdx.y*64;
  int tid = threadIdx.x;
  int c4 = (tid & 15)*4, rr = tid >> 4;
  #pragma unroll
  for (int p = 0; p < 4; ++p) {
    int row = p*16 + rr;
    float4 v = *(const float4*)(W + (size_t)(k0+row)*ncols + n0 + c4);
    T[c4+0][row] = v.x; T[c4+1][row] = v.y; T[c4+2][row] = v.z; T[c4+3][row] = v.w;
  }
  __syncthreads();
  #pragma unroll
  for (int p = 0; p < 4; ++p) {
    int cc = p*16 + rr;
    bf16x4 o;
    o[0] = (__bf16)T[cc][c4+0]; o[1] = (__bf16)T[cc][c4+1];
    o[2] = (__bf16)T[cc][c4+2]; o[3] = (__bf16)T[cc][c4+3];
    *(bf16x4*)(D + (size_t)(n0+cc)*256 + k0 + c4) = o;
  }
}

// ---------------- pooled tokens: transpose [c][tok] fp32 -> [tok][c] bf16 ----------------
__global__ __launch_bounds__(256) void transpose_tok(
    const float* __restrict__ mid, const float* __restrict__ glb,
    __bf16* __restrict__ mgt)
{
  __shared__ float T[64][68];
  int t0 = blockIdx.x*64, c0 = blockIdx.y*64, b = blockIdx.z;
  const float* src; int stride, toff;
  if (t0 < 1024) { src = mid + ((size_t)(b*256 + c0))*1024; stride = 1024; toff = t0; }
  else           { src = glb + ((size_t)(b*256 + c0))*256;  stride = 256;  toff = t0 - 1024; }
  int tid = threadIdx.x;
  int c4 = (tid & 15)*4, rr = tid >> 4;
  #pragma unroll
  for (int p = 0; p < 4; ++p) {
    int row = p*16 + rr;                 // channel offset
    float4 v = *(const float4*)(src + (size_t)row*stride + toff + c4);
    T[c4+0][row] = v.x; T[c4+1][row] = v.y; T[c4+2][row] = v.z; T[c4+3][row] = v.w;
  }
  __syncthreads();
  #pragma unroll
  for (int p = 0; p < 4; ++p) {
    int tt = p*16 + rr;                  // token offset
    bf16x4 o;
    o[0] = (__bf16)T[tt][c4+0]; o[1] = (__bf16)T[tt][c4+1];
    o[2] = (__bf16)T[tt][c4+2]; o[3] = (__bf16)T[tt][c4+3];
    *(bf16x4*)(mgt + ((size_t)b*1280 + t0 + tt)*256 + c0 + c4) = o;
  }
}

// ---------------- q GEMM v2: WT[0:256] LDS-staged (kills 16-line split loads) ----------------
// block = 64 tokens x 128-col half; wave = 16 tokens; A = staged WT rows (m=n-col),
// B = token fragments from qnb (8 split loads once per wave). Dbuf, dist-2 prefetch.
__global__ __launch_bounds__(256) void gemm_q_mfma(
    const __bf16* __restrict__ qnb, const __bf16* __restrict__ WT,
    const float* __restrict__ qkvb, __bf16* __restrict__ qbf)
{
  __shared__ __bf16 Bs[2][16*264];     // 16.5 KB
  int blk = blockIdx.x;                // tb*2 + nh, grid 256
  int tb = blk >> 1, nh = blk & 1;
  int n0 = nh*128;
  int tid = threadIdx.x, wv = tid >> 6, lane = tid & 63;
  int col = lane & 15, quad = lane >> 4;
  int m0 = tb*64 + wv*16;

  bf16x8 bq[8];
  const __bf16* qp = qnb + ((size_t)(m0 + col))*256 + quad*8;
  #pragma unroll
  for (int kk = 0; kk < 8; ++kk) bq[kk] = *(const bf16x8*)(qp + kk*32);

  int brow = tid >> 4, bseg = tid & 15;
  const __bf16* wsrc = WT + ((size_t)(n0 + brow))*256 + bseg*16;
  {
    bf16x8 a0 = *(const bf16x8*)wsrc;
    bf16x8 a1 = *(const bf16x8*)(wsrc + 8);
    __bf16* d = &Bs[0][0] + brow*264 + bseg*16;
    *(bf16x8*)d = a0; *(bf16x8*)(d + 8) = a1;
  }
  bf16x8 g0 = *(const bf16x8*)(wsrc + (size_t)4096);
  bf16x8 g1 = *(const bf16x8*)(wsrc + (size_t)4096 + 8);
  __syncthreads();

  const f32x4 zero = {0.f,0.f,0.f,0.f};
  #pragma unroll 1
  for (int s = 0; s < 8; ++s) {
    if (s < 7) {
      __bf16* d = &Bs[(s+1) & 1][0] + brow*264 + bseg*16;
      *(bf16x8*)d = g0; *(bf16x8*)(d + 8) = g1;
    }
    if (s < 6) {
      const __bf16* p = wsrc + (size_t)(s+2)*4096;
      g0 = *(const bf16x8*)p; g1 = *(const bf16x8*)(p + 8);
    }
    const __bf16* Ab = &Bs[s & 1][0] + col*264 + quad*8;
    f32x4 acc = zero;
    #pragma unroll
    for (int kk = 0; kk < 8; ++kk) {
      bf16x8 wf = *(const bf16x8*)(Ab + kk*32);
      acc = __builtin_amdgcn_mfma_f32_16x16x32_bf16(wf, bq[kk], acc, 0, 0, 0);
    }
    int nq4 = n0 + s*16 + quad*4;
    float4 b4 = *(const float4*)(qkvb + nq4);
    float bb[4] = {b4.x, b4.y, b4.z, b4.w};
    bf16x4 o;
    #pragma unroll
    for (int r = 0; r < 4; ++r) o[r] = (__bf16)((acc[r]+bb[r])*QSCALE_L2E);
    *(bf16x4*)(qbf + ((size_t)(m0 + col))*256 + nq4) = o;
    __syncthreads();
  }
}

// ---------------- local KV v4: direct register A-frags, Bs-only LDS ----------------
__global__ __launch_bounds__(256) void loc_kv_mfma(
    const float* __restrict__ F, const __bf16* __restrict__ WT,
    const float* __restrict__ qkvb,
    __bf16* __restrict__ kloc, __bf16* __restrict__ vloct)
{
  __shared__ __bf16 Bs[2][16*264];     // 16.5 KB
  int bw = blockIdx.x;
  int b = bw >> 8, w = bw & 255;
  int wy = w >> 4, wx = w & 15;
  int tid = threadIdx.x;
  int wv = tid >> 6, lane = tid & 63;
  int col = lane & 15, quad = lane >> 4;
  int m0 = wv*16;

  // ---- direct A-frag loads: 8 contiguous x-pixels of one F row per kk ----
  bf16x8 af[8];
  int x0 = wx*4 - 2;
  bool p0ok = (wx > 0), p3ok = (wx < 15);
  const float* Fb = F + ((size_t)(b*256 + 4*(m0+col)))*HWSZ;
  #pragma unroll
  for (int kk = 0; kk < 8; ++kk) {
    int r = kk >> 1;
    int y = wy*4 + (kk & 1)*4 + quad - 2;
    bool yok = ((unsigned)y < 64u);
    const float* row = Fb + (size_t)r*HWSZ + y*64 + x0;
    float2 v0 = make_float2(0.f,0.f), v1 = make_float2(0.f,0.f);
    float2 v2 = make_float2(0.f,0.f), v3 = make_float2(0.f,0.f);
    if (yok) {
      if (p0ok) v0 = *(const float2*)(row);
      v1 = *(const float2*)(row + 2);
      v2 = *(const float2*)(row + 4);
      if (p3ok) v3 = *(const float2*)(row + 6);
    }
    af[kk][0] = (__bf16)v0.x; af[kk][1] = (__bf16)v0.y;
    af[kk][2] = (__bf16)v1.x; af[kk][3] = (__bf16)v1.y;
    af[kk][4] = (__bf16)v2.x; af[kk][5] = (__bf16)v2.y;
    af[kk][6] = (__bf16)v3.x; af[kk][7] = (__bf16)v3.y;
  }

  int brow = tid >> 4, bseg = tid & 15;
  const __bf16* wsrc = WT + ((size_t)(256 + brow))*256 + bseg*16;
  __bf16* bd0 = &Bs[0][0] + brow*264 + bseg*16;
  {
    bf16x8 a0 = *(const bf16x8*)wsrc;
    bf16x8 a1 = *(const bf16x8*)(wsrc + 8);
    *(bf16x8*)bd0 = a0;
    *(bf16x8*)(bd0 + 8) = a1;
  }
  bf16x8 g0 = *(const bf16x8*)(wsrc + (size_t)4096);
  bf16x8 g1 = *(const bf16x8*)(wsrc + (size_t)4096 + 8);
  __syncthreads();

  const f32x4 zero = {0.f,0.f,0.f,0.f};
  #pragma unroll 1
  for (int nt = 0; nt < 32; ++nt) {
    if (nt < 31) {
      __bf16* d = &Bs[(nt+1) & 1][0] + brow*264 + bseg*16;
      *(bf16x8*)d = g0;
      *(bf16x8*)(d + 8) = g1;
    }
    if (nt < 30) {
      const __bf16* p = wsrc + (size_t)(nt+2)*4096;
      g0 = *(const bf16x8*)p;
      g1 = *(const bf16x8*)(p + 8);
    }
    int n = nt*16 + col;
    float bias_n = qkvb[256 + n];
    const __bf16* Bb = &Bs[nt & 1][0] + col*264 + quad*8;
    f32x4 acc = zero;
    #pragma unroll
    for (int kk = 0; kk < 8; ++kk) {
      bf16x8 bv = *(const bf16x8*)(Bb + kk*32);
      acc = __builtin_amdgcn_mfma_f32_16x16x32_bf16(af[kk], bv, acc, 0, 0, 0);
    }
    if (nt < 16) {
      #pragma unroll
      for (int r = 0; r < 4; ++r)
        kloc[((size_t)bw*64 + m0 + quad*4 + r)*256 + n] = (__bf16)(acc[r] + bias_n);
    } else {
      bf16x4 o;
      #pragma unroll
      for (int r = 0; r < 4; ++r) o[r] = (__bf16)(acc[r] + bias_n);
      *(bf16x4*)(vloct + ((size_t)bw*256 + (n - 256))*64 + m0 + quad*4) = o;
    }
    __syncthreads();
  }
}

// ---------------- mid/glb KV v2: WT[256+n0..] LDS-staged ----------------
__global__ __launch_bounds__(256) void mg_kv_mfma(
    const __bf16* __restrict__ mgt, const __bf16* __restrict__ WT,
    const float* __restrict__ qkvb,
    __bf16* __restrict__ kmg, __bf16* __restrict__ vmgt)
{
  __shared__ __bf16 Bs[2][16*264];     // 16.5 KB
  int tb = blockIdx.x, nq = blockIdx.y, b = blockIdx.z;   // grid (20,4,2)
  int tid = threadIdx.x, wv = tid >> 6, lane = tid & 63;
  int col = lane & 15, quad = lane >> 4;
  int m0 = tb*64 + wv*16;
  int n0 = nq*128;

  const __bf16* Ab = mgt + ((size_t)b*1280 + m0 + col)*256 + quad*8;
  bf16x8 af[8];
  #pragma unroll
  for (int kk = 0; kk < 8; ++kk) af[kk] = *(const bf16x8*)(Ab + kk*32);

  int brow = tid >> 4, bseg = tid & 15;
  const __bf16* wsrc = WT + ((size_t)(256 + n0 + brow))*256 + bseg*16;
  {
    bf16x8 a0 = *(const bf16x8*)wsrc;
    bf16x8 a1 = *(const bf16x8*)(wsrc + 8);
    __bf16* d = &Bs[0][0] + brow*264 + bseg*16;
    *(bf16x8*)d = a0; *(bf16x8*)(d + 8) = a1;
  }
  bf16x8 g0 = *(const bf16x8*)(wsrc + (size_t)4096);
  bf16x8 g1 = *(const bf16x8*)(wsrc + (size_t)4096 + 8);
  __syncthreads();

  const f32x4 zero = {0.f,0.f,0.f,0.f};
  #pragma unroll 1
  for (int s = 0; s < 8; ++s) {
    if (s < 7) {
      __bf16* d = &Bs[(s+1) & 1][0] + brow*264 + bseg*16;
      *(bf16x8*)d = g0; *(bf16x8*)(d + 8) = g1;
    }
    if (s < 6) {
      const __bf16* p = wsrc + (size_t)(s+2)*4096;
      g0 = *(const bf16x8*)p; g1 = *(const bf16x8*)(p + 8);
    }
    int n = n0 + s*16 + col;
    float bias_n = qkvb[256 + n];
    const __bf16* Bb = &Bs[s & 1][0] + col*264 + quad*8;
    f32x4 acc = zero;
    #pragma unroll
    for (int kk = 0; kk < 8; ++kk) {
      bf16x8 bv = *(const bf16x8*)(Bb + kk*32);
      acc = __builtin_amdgcn_mfma_f32_16x16x32_bf16(af[kk], bv, acc, 0, 0, 0);
    }
    if (n < 256) {
      #pragma unroll
      for (int r = 0; r < 4; ++r)
        kmg[((size_t)b*1280 + m0 + quad*4 + r)*256 + n] = (__bf16)(acc[r] + bias_n);
    } else {
      bf16x4 o;
      #pragma unroll
      for (int r = 0; r < 4; ++r) o[r] = (__bf16)(acc[r] + bias_n);
      *(bf16x4*)(vmgt + ((size_t)b*256 + (n - 256))*1280 + m0 + quad*4) = o;
    }
    __syncthreads();
  }
}

// ---------------- MFMA fused attention (r8 version: LDS K/V staging, 8 waves) ----------------
__global__ __launch_bounds__(512) void attn_mfma(
    const __bf16* __restrict__ qbf, const __bf16* __restrict__ kloc,
    const __bf16* __restrict__ vloct, const __bf16* __restrict__ kmg,
    const __bf16* __restrict__ vmgt, __bf16* __restrict__ obf)
{
  __shared__ __bf16 Ks[3][32][40];
  __shared__ __bf16 Vs[3][32][40];
  __shared__ __bf16 Pb[8][2][16][40];
  int blk = blockIdx.x;
  int b = blk >> 8, rr = blk & 255;
  int h = rr >> 5, wg = rr & 31;
  int tid = threadIdx.x, wv = tid >> 6, lane = tid & 63;
  int col = lane & 15, quad = lane >> 4;
  int bw = b*256 + wg*8 + wv;           // this wave's window

  int r64 = tid >> 3, l8 = tid & 7;
  bool isK = r64 < 32;
  int srow = isK ? r64 : r64 - 32;
  const __bf16* gbase = isK
      ? kmg  + ((size_t)(b*1280 + srow))*256 + h*32 + l8*4
      : vmgt + ((size_t)(b*256 + h*32 + srow))*1280 + l8*4;
  size_t gstride = isK ? 256 : 1;
  __bf16* lbase = isK ? &Ks[0][srow][l8*4] : &Vs[0][srow][l8*4];

  bf16x8 aq = *(const bf16x8*)(qbf + ((size_t)(bw*16 + col))*256 + h*32 + quad*8);
  f32x4 O0 = {0.f,0.f,0.f,0.f}, O1 = {0.f,0.f,0.f,0.f};
  const f32x4 zero = {0.f,0.f,0.f,0.f};
  float ls[4] = {0.f,0.f,0.f,0.f};
  __bf16* PwBase = &Pb[wv][0][0][0];

  bf16x4 sreg = *(const bf16x4*)gbase;

  const __bf16* klocb = kloc  + (size_t)bw*16384 + h*32 + quad*8;
  const __bf16* vlocb = vloct + (size_t)bw*16384 + (size_t)(h*32)*64 + quad*8;
  #pragma unroll
  for (int ch = 0; ch < 2; ++ch) {
    bf16x8 k0 = *(const bf16x8*)(klocb + (size_t)(ch*32 + col)*256);
    bf16x8 k1 = *(const bf16x8*)(klocb + (size_t)(ch*32 + 16 + col)*256);
    bf16x8 v0 = *(const bf16x8*)(vlocb + (size_t)col*64 + ch*32);
    bf16x8 v1 = *(const bf16x8*)(vlocb + (size_t)(16+col)*64 + ch*32);
    f32x4 S0 = __builtin_amdgcn_mfma_f32_16x16x32_bf16(aq, k0, zero, 0, 0, 0);
    f32x4 S1 = __builtin_amdgcn_mfma_f32_16x16x32_bf16(aq, k1, zero, 0, 0, 0);
    __bf16* Pw = PwBase + (ch & 1)*640;
    #pragma unroll
    for (int r = 0; r < 4; ++r) {
      float p0 = __builtin_amdgcn_exp2f(S0[r]);
      float p1 = __builtin_amdgcn_exp2f(S1[r]);
      ls[r] += p0 + p1;
      Pw[(quad*4+r)*40 + col]      = (__bf16)p0;
      Pw[(quad*4+r)*40 + 16 + col] = (__bf16)p1;
    }
    bf16x8 ap = *(const bf16x8*)(Pw + (size_t)col*40 + quad*8);
    O0 = __builtin_amdgcn_mfma_f32_16x16x32_bf16(ap, v0, O0, 0, 0, 0);
    O1 = __builtin_amdgcn_mfma_f32_16x16x32_bf16(ap, v1, O1, 0, 0, 0);
  }

  *(bf16x4*)(lbase + 2*1280) = sreg;
  sreg = *(const bf16x4*)(gbase + (size_t)32*gstride);
  __syncthreads();

  int buf = 2;
  #pragma unroll 1
  for (int ch = 2; ch < 42; ++ch) {
    int nbuf = (buf == 2) ? 0 : buf + 1;
    if (ch + 1 < 42) {
      *(bf16x4*)(lbase + nbuf*1280) = sreg;
      if (ch + 2 < 42)
        sreg = *(const bf16x4*)(gbase + (size_t)(ch*32)*gstride);
    }
    const __bf16* Kb = &Ks[buf][0][0];
    const __bf16* Vb = &Vs[buf][0][0];
    bf16x8 k0 = *(const bf16x8*)(Kb + col*40 + quad*8);
    bf16x8 k1 = *(const bf16x8*)(Kb + (16+col)*40 + quad*8);
    bf16x8 v0 = *(const bf16x8*)(Vb + col*40 + quad*8);
    bf16x8 v1 = *(const bf16x8*)(Vb + (16+col)*40 + quad*8);
    f32x4 S0 = __builtin_amdgcn_mfma_f32_16x16x32_bf16(aq, k0, zero, 0, 0, 0);
    f32x4 S1 = __builtin_amdgcn_mfma_f32_16x16x32_bf16(aq, k1, zero, 0, 0, 0);
    __bf16* Pw = PwBase + (ch & 1)*640;
    #pragma unroll
    for (int r = 0; r < 4; ++r) {
      float p0 = __builtin_amdgcn_exp2f(S0[r]);
      float p1 = __builtin_amdgcn_exp2f(S1[r]);
      ls[r] += p0 + p1;
      Pw[(quad*4+r)*40 + col]      = (__bf16)p0;
      Pw[(quad*4+r)*40 + 16 + col] = (__bf16)p1;
    }
    bf16x8 ap = *(const bf16x8*)(Pw + (size_t)col*40 + quad*8);
    O0 = __builtin_amdgcn_mfma_f32_16x16x32_bf16(ap, v0, O0, 0, 0, 0);
    O1 = __builtin_amdgcn_mfma_f32_16x16x32_bf16(ap, v1, O1, 0, 0, 0);
    buf = nbuf;
    __syncthreads();
  }

  #pragma unroll
  for (int r = 0; r < 4; ++r) {
    #pragma unroll
    for (int m = 1; m < 16; m <<= 1) ls[r] += __shfl_xor(ls[r], m);
  }
  __bf16* op = obf + ((size_t)(bw*16) + quad*4)*256 + h*32 + col;
  #pragma unroll
  for (int r = 0; r < 4; ++r) {
    float inv = 1.f / ls[r];
    op[(size_t)r*256]      = (__bf16)(O0[r]*inv);
    op[(size_t)r*256 + 16] = (__bf16)(O1[r]*inv);
  }
}

// ---------------- out projection v2: WoT tiles LDS-staged (stage-all, 1 barrier) ----------------
__global__ __launch_bounds__(256) void gemm_out_strip(
    const __bf16* __restrict__ obf, const __bf16* __restrict__ WoT,
    const float* __restrict__ outb, const float* __restrict__ Fres,
    float* __restrict__ Out)
{
  __shared__ __bf16 Bs4[4*16*264];     // 33 KB: this block's 4 WoT tiles
  __shared__ __bf16 strip[64*264];     // 33 KB
  int blk = blockIdx.x;                // b*64 + wy*4 + cq
  int b = blk >> 6, wy = (blk >> 2) & 15, cq = blk & 3;
  int c0 = cq*64;
  int tid = threadIdx.x, wv = tid >> 6, lane = tid & 63;
  int col = lane & 15, quad = lane >> 4;
  const f32x4 zero = {0.f,0.f,0.f,0.f};

  // stage all 4 tiles (rows c0..c0+63) with coalesced 32 B/thread loads
  {
    int brow = tid >> 4, bseg = tid & 15;
    const __bf16* wsrc = WoT + ((size_t)(c0 + brow))*256 + bseg*16;
    #pragma unroll
    for (int s = 0; s < 4; ++s) {
      bf16x8 a0 = *(const bf16x8*)(wsrc + (size_t)s*4096);
      bf16x8 a1 = *(const bf16x8*)(wsrc + (size_t)s*4096 + 8);
      __bf16* d = Bs4 + s*4224 + brow*264 + bseg*16;
      *(bf16x8*)d = a0; *(bf16x8*)(d + 8) = a1;
    }
  }
  __syncthreads();

  #pragma unroll
  for (int i = 0; i < 4; ++i) {
    int wx = wv*4 + i;
    int win = b*256 + wy*16 + wx;
    bf16x8 ao[8];
    const __bf16* op = obf + ((size_t)win*16 + col)*256 + quad*8;
    #pragma unroll
    for (int kk = 0; kk < 8; ++kk) ao[kk] = *(const bf16x8*)(op + kk*32);
    #pragma unroll
    for (int nt = 0; nt < 4; ++nt) {
      const __bf16* Bb = Bs4 + nt*4224 + col*264 + quad*8;
      f32x4 acc = zero;
      #pragma unroll
      for (int kk = 0; kk < 8; ++kk) {
        bf16x8 wf = *(const bf16x8*)(Bb + kk*32);
        acc = __builtin_amdgcn_mfma_f32_16x16x32_bf16(ao[kk], wf, acc, 0, 0, 0);
      }
      bf16x4 o;
      #pragma unroll
      for (int r = 0; r < 4; ++r) o[r] = (__bf16)acc[r];
      *(bf16x4*)&strip[(nt*16+col)*264 + quad*66 + wx*4] = o;
    }
  }
  __syncthreads();
  #pragma unroll
  for (int j = 0; j < 16; ++j) {
    int f4 = j*256 + tid;               // [c][y][xq]
    int xq = f4 & 15, y = (f4 >> 4) & 3, c = f4 >> 6;
    bf16x4 d = *(const bf16x4*)&strip[c*264 + y*66 + xq*4];
    size_t off = ((size_t)(b*256 + c0 + c))*HWSZ + (wy*4 + y)*64 + xq*4;
    float4 r4 = *(const float4*)(Fres + off);
    float bn = outb[c0 + c];
    float4 o;
    o.x = (float)d[0] + bn + r4.x; o.y = (float)d[1] + bn + r4.y;
    o.z = (float)d[2] + bn + r4.z; o.w = (float)d[3] + bn + r4.w;
    *(float4*)(Out + off) = o;
  }
}

extern "C" void kernel_launch(void* const* d_in, const int* in_sizes, int n_in,
                              void* d_out, int out_size, void* d_ws, size_t ws_size,
                              hipStream_t stream) {
  const float* F     = (const float*)d_in[0];
  const float* qkv_w = (const float*)d_in[1];
  const float* qkv_b = (const float*)d_in[2];
  const float* out_w = (const float*)d_in[3];
  const float* out_b = (const float*)d_in[4];
  const float* ln_w  = (const float*)d_in[5];
  const float* ln_b  = (const float*)d_in[6];
  float* out = (float*)d_out;

  __bf16* qnb   = (__bf16*)d_ws;             // 2,097,152 h
  __bf16* qbf   = qnb   + 2097152;           // 2,097,152 h
  __bf16* obf   = qbf   + 2097152;           // 2,097,152 h
  __bf16* kloc  = obf   + 2097152;           // 8,388,608 h
  __bf16* vloct = kloc  + 8388608;           // 8,388,608 h
  __bf16* kmg   = vloct + 8388608;           // 655,360 h
  __bf16* vmgt  = kmg   + 655360;            // 655,360 h
  __bf16* mgt   = vmgt  + 655360;            // 655,360 h
  __bf16* WT    = mgt   + 655360;            // 196,608 h
  __bf16* WoT   = WT    + 196608;            // 65,536 h
  float*  mid   = (float*)(WoT + 65536);     // 524,288 f
  float*  glb   = mid   + 524288;            // 131,072 f

  transpose_ws<<<dim3(16, 4), 256, 0, stream>>>(qkv_w, out_w, WT, WoT);
  ln_qn_kernel<<<512, 256, 0, stream>>>(F, ln_w, ln_b, qnb);
  pool_kernel<<<512, 256, 0, stream>>>(F, mid, glb);
  transpose_tok<<<dim3(20, 4, 2), 256, 0, stream>>>(mid, glb, mgt);
  gemm_q_mfma<<<256, 256, 0, stream>>>(qnb, WT, qkv_b, qbf);
  loc_kv_mfma<<<512, 256, 0, stream>>>(F, WT, qkv_b, kloc, vloct);
  mg_kv_mfma<<<dim3(20, 4, 2), 256, 0, stream>>>(mgt, WT, qkv_b, kmg, vmgt);
  attn_mfma<<<512, 512, 0, stream>>>(qbf, kloc, vloct, kmg, vmgt, obf);
  gemm_out_strip<<<128, 256, 0, stream>>>(obf, WoT, out_b, F, out);
}

// Round 13
// 161.770 us; speedup vs baseline: 1.2746x; 1.0383x over previous
//
#include <hip/hip_runtime.h>
#include <math.h>

#define HWSZ 4096   // 64*64
// 1/sqrt(32) * log2(e): scores come out pre-multiplied by log2(e), so softmax
// uses p = exp2(S) (single v_exp_f32) -- mathematically identical.
#define QSCALE_L2E 0.25501988932587245f

typedef __bf16 bf16x2 __attribute__((ext_vector_type(2)));
typedef __bf16 bf16x4 __attribute__((ext_vector_type(4)));
typedef __bf16 bf16x8 __attribute__((ext_vector_type(8)));
typedef float  f32x4  __attribute__((ext_vector_type(4)));

// ---------------- scrambled-token LayerNorm, strip version ----------------
__global__ __launch_bounds__(256) void ln_qn_kernel(
    const float* __restrict__ F, const float* __restrict__ lnw,
    const float* __restrict__ lnb, __bf16* __restrict__ qnb)
{
  __shared__ float sm[16*269];         // [c16] stride 269, [py] stride 67, [x]
  int blk = blockIdx.x;                // b*256 + wy*16 + t
  int b = blk >> 8, wy = (blk >> 4) & 15, t = blk & 15;
  int tid = threadIdx.x;
  const float* Fb = F + ((size_t)(b*256 + t*16))*HWSZ + (wy*4)*64;
  int py = tid >> 6, x = tid & 63;
  #pragma unroll
  for (int j = 0; j < 16; ++j)
    sm[j*269 + py*67 + x] = Fb[(size_t)j*HWSZ + py*64 + x];
  __syncthreads();
  int wx = tid >> 4, cl = tid & 15;    // window wx, channel-lane cl
  float vals[16], s1 = 0.f, s2 = 0.f;
  #pragma unroll
  for (int p = 0; p < 16; ++p) {
    float v = sm[cl*269 + (p >> 2)*67 + wx*4 + (p & 3)];
    vals[p] = v; s1 += v; s2 += v*v;
  }
  #pragma unroll
  for (int m = 1; m < 16; m <<= 1) { s1 += __shfl_xor(s1, m); s2 += __shfl_xor(s2, m); }
  float mean = s1 * (1.f/256.f);
  float var  = s2 * (1.f/256.f) - mean*mean;
  float rstd = rsqrtf(var + 1e-5f);
  __bf16* outp = qnb + (((size_t)(b*256 + wy*16 + wx))*16 + t)*256 + cl*16;
  bf16x8 o0, o1;
  #pragma unroll
  for (int p = 0; p < 8; ++p) {
    o0[p] = (__bf16)((vals[p]  -mean)*rstd*lnw[cl*16+p]   + lnb[cl*16+p]);
    o1[p] = (__bf16)((vals[p+8]-mean)*rstd*lnw[cl*16+p+8] + lnb[cl*16+p+8]);
  }
  *(bf16x8*)outp = o0;
  *(bf16x8*)(outp+8) = o1;
}

// ---------------- fused pools: thread = 2x2 mid patch -> 1 glb elem ----------------
__global__ __launch_bounds__(256) void pool_kernel(
    const float* __restrict__ F, float* __restrict__ mid, float* __restrict__ glb)
{
  int bc = blockIdx.x;                  // b*256 + c
  int t = threadIdx.x;
  int gy = t >> 4, gx = t & 15;
  const float* p = F + (size_t)bc*HWSZ + (gy*4)*64 + gx*4;
  float4 r0 = *(const float4*)(p);
  float4 r1 = *(const float4*)(p + 64);
  float4 r2 = *(const float4*)(p + 128);
  float4 r3 = *(const float4*)(p + 192);
  float m00 = 0.25f*(r0.x + r0.y + r1.x + r1.y);
  float m01 = 0.25f*(r0.z + r0.w + r1.z + r1.w);
  float m10 = 0.25f*(r2.x + r2.y + r3.x + r3.y);
  float m11 = 0.25f*(r2.z + r2.w + r3.z + r3.w);
  float* mp = mid + (size_t)bc*1024 + (gy*2)*32 + gx*2;
  *(float2*)mp        = make_float2(m00, m01);
  *(float2*)(mp + 32) = make_float2(m10, m11);
  glb[(size_t)bc*256 + gy*16 + gx] = 0.25f*(m00 + m01 + m10 + m11);
}

// ---------------- one-time: all transposes in ONE dispatch ----------------
// bx<12: qkv_w -> WT; bx<16: out_w -> WoT; bx>=16: pooled tokens -> mgt
__global__ __launch_bounds__(256) void transpose_all(
    const float* __restrict__ Wqkv, const float* __restrict__ Wout,
    const float* __restrict__ mid, const float* __restrict__ glb,
    __bf16* __restrict__ WT, __bf16* __restrict__ WoT, __bf16* __restrict__ mgt)
{
  __shared__ float T[64][68];
  int bx = blockIdx.x;
  int tid = threadIdx.x;
  int c4 = (tid & 15)*4, rr = tid >> 4;
  if (bx < 16) {
    const float* W; __bf16* D; int ncols, n0;
    if (bx < 12) { W = Wqkv; D = WT;  ncols = 768; n0 = bx*64; }
    else         { W = Wout; D = WoT; ncols = 256; n0 = (bx-12)*64; }
    int k0 = blockIdx.y*64;
    #pragma unroll
    for (int p = 0; p < 4; ++p) {
      int row = p*16 + rr;
      float4 v = *(const float4*)(W + (size_t)(k0+row)*ncols + n0 + c4);
      T[c4+0][row] = v.x; T[c4+1][row] = v.y; T[c4+2][row] = v.z; T[c4+3][row] = v.w;
    }
    __syncthreads();
    #pragma unroll
    for (int p = 0; p < 4; ++p) {
      int cc = p*16 + rr;
      bf16x4 o;
      o[0] = (__bf16)T[cc][c4+0]; o[1] = (__bf16)T[cc][c4+1];
      o[2] = (__bf16)T[cc][c4+2]; o[3] = (__bf16)T[cc][c4+3];
      *(bf16x4*)(D + (size_t)(n0+cc)*256 + k0 + c4) = o;
    }
  } else {
    int tt = bx - 16;                    // 0..39
    int b = tt / 20, tq = tt % 20;
    int t0 = tq*64, c0 = blockIdx.y*64;
    const float* src; int stride, toff;
    if (t0 < 1024) { src = mid + ((size_t)(b*256 + c0))*1024; stride = 1024; toff = t0; }
    else           { src = glb + ((size_t)(b*256 + c0))*256;  stride = 256;  toff = t0 - 1024; }
    #pragma unroll
    for (int p = 0; p < 4; ++p) {
      int row = p*16 + rr;               // channel offset
      float4 v = *(const float4*)(src + (size_t)row*stride + toff + c4);
      T[c4+0][row] = v.x; T[c4+1][row] = v.y; T[c4+2][row] = v.z; T[c4+3][row] = v.w;
    }
    __syncthreads();
    #pragma unroll
    for (int p = 0; p < 4; ++p) {
      int t2 = p*16 + rr;                // token offset
      bf16x4 o;
      o[0] = (__bf16)T[t2][c4+0]; o[1] = (__bf16)T[t2][c4+1];
      o[2] = (__bf16)T[t2][c4+2]; o[3] = (__bf16)T[t2][c4+3];
      *(bf16x4*)(mgt + ((size_t)b*1280 + t0 + t2)*256 + c0 + c4) = o;
    }
  }
}

// ---------------- q GEMM v2: WT[0:256] LDS-staged ----------------
__global__ __launch_bounds__(256) void gemm_q_mfma(
    const __bf16* __restrict__ qnb, const __bf16* __restrict__ WT,
    const float* __restrict__ qkvb, __bf16* __restrict__ qbf)
{
  __shared__ __bf16 Bs[2][16*264];     // 16.5 KB
  int blk = blockIdx.x;                // tb*2 + nh, grid 256
  int tb = blk >> 1, nh = blk & 1;
  int n0 = nh*128;
  int tid = threadIdx.x, wv = tid >> 6, lane = tid & 63;
  int col = lane & 15, quad = lane >> 4;
  int m0 = tb*64 + wv*16;

  bf16x8 bq[8];
  const __bf16* qp = qnb + ((size_t)(m0 + col))*256 + quad*8;
  #pragma unroll
  for (int kk = 0; kk < 8; ++kk) bq[kk] = *(const bf16x8*)(qp + kk*32);

  int brow = tid >> 4, bseg = tid & 15;
  const __bf16* wsrc = WT + ((size_t)(n0 + brow))*256 + bseg*16;
  {
    bf16x8 a0 = *(const bf16x8*)wsrc;
    bf16x8 a1 = *(const bf16x8*)(wsrc + 8);
    __bf16* d = &Bs[0][0] + brow*264 + bseg*16;
    *(bf16x8*)d = a0; *(bf16x8*)(d + 8) = a1;
  }
  bf16x8 g0 = *(const bf16x8*)(wsrc + (size_t)4096);
  bf16x8 g1 = *(const bf16x8*)(wsrc + (size_t)4096 + 8);
  __syncthreads();

  const f32x4 zero = {0.f,0.f,0.f,0.f};
  #pragma unroll 1
  for (int s = 0; s < 8; ++s) {
    if (s < 7) {
      __bf16* d = &Bs[(s+1) & 1][0] + brow*264 + bseg*16;
      *(bf16x8*)d = g0; *(bf16x8*)(d + 8) = g1;
    }
    if (s < 6) {
      const __bf16* p = wsrc + (size_t)(s+2)*4096;
      g0 = *(const bf16x8*)p; g1 = *(const bf16x8*)(p + 8);
    }
    const __bf16* Ab = &Bs[s & 1][0] + col*264 + quad*8;
    f32x4 acc = zero;
    #pragma unroll
    for (int kk = 0; kk < 8; ++kk) {
      bf16x8 wf = *(const bf16x8*)(Ab + kk*32);
      acc = __builtin_amdgcn_mfma_f32_16x16x32_bf16(wf, bq[kk], acc, 0, 0, 0);
    }
    int nq4 = n0 + s*16 + quad*4;
    float4 b4 = *(const float4*)(qkvb + nq4);
    float bb[4] = {b4.x, b4.y, b4.z, b4.w};
    bf16x4 o;
    #pragma unroll
    for (int r = 0; r < 4; ++r) o[r] = (__bf16)((acc[r]+bb[r])*QSCALE_L2E);
    *(bf16x4*)(qbf + ((size_t)(m0 + col))*256 + nq4) = o;
    __syncthreads();
  }
}

// ---------------- local KV v4: direct register A-frags, Bs-only LDS ----------------
__global__ __launch_bounds__(256) void loc_kv_mfma(
    const float* __restrict__ F, const __bf16* __restrict__ WT,
    const float* __restrict__ qkvb,
    __bf16* __restrict__ kloc, __bf16* __restrict__ vloct)
{
  __shared__ __bf16 Bs[2][16*264];     // 16.5 KB
  int bw = blockIdx.x;
  int b = bw >> 8, w = bw & 255;
  int wy = w >> 4, wx = w & 15;
  int tid = threadIdx.x;
  int wv = tid >> 6, lane = tid & 63;
  int col = lane & 15, quad = lane >> 4;
  int m0 = wv*16;

  // ---- direct A-frag loads: 8 contiguous x-pixels of one F row per kk ----
  bf16x8 af[8];
  int x0 = wx*4 - 2;
  bool p0ok = (wx > 0), p3ok = (wx < 15);
  const float* Fb = F + ((size_t)(b*256 + 4*(m0+col)))*HWSZ;
  #pragma unroll
  for (int kk = 0; kk < 8; ++kk) {
    int r = kk >> 1;
    int y = wy*4 + (kk & 1)*4 + quad - 2;
    bool yok = ((unsigned)y < 64u);
    const float* row = Fb + (size_t)r*HWSZ + y*64 + x0;
    float2 v0 = make_float2(0.f,0.f), v1 = make_float2(0.f,0.f);
    float2 v2 = make_float2(0.f,0.f), v3 = make_float2(0.f,0.f);
    if (yok) {
      if (p0ok) v0 = *(const float2*)(row);
      v1 = *(const float2*)(row + 2);
      v2 = *(const float2*)(row + 4);
      if (p3ok) v3 = *(const float2*)(row + 6);
    }
    af[kk][0] = (__bf16)v0.x; af[kk][1] = (__bf16)v0.y;
    af[kk][2] = (__bf16)v1.x; af[kk][3] = (__bf16)v1.y;
    af[kk][4] = (__bf16)v2.x; af[kk][5] = (__bf16)v2.y;
    af[kk][6] = (__bf16)v3.x; af[kk][7] = (__bf16)v3.y;
  }

  int brow = tid >> 4, bseg = tid & 15;
  const __bf16* wsrc = WT + ((size_t)(256 + brow))*256 + bseg*16;
  __bf16* bd0 = &Bs[0][0] + brow*264 + bseg*16;
  {
    bf16x8 a0 = *(const bf16x8*)wsrc;
    bf16x8 a1 = *(const bf16x8*)(wsrc + 8);
    *(bf16x8*)bd0 = a0;
    *(bf16x8*)(bd0 + 8) = a1;
  }
  bf16x8 g0 = *(const bf16x8*)(wsrc + (size_t)4096);
  bf16x8 g1 = *(const bf16x8*)(wsrc + (size_t)4096 + 8);
  __syncthreads();

  const f32x4 zero = {0.f,0.f,0.f,0.f};
  #pragma unroll 1
  for (int nt = 0; nt < 32; ++nt) {
    if (nt < 31) {
      __bf16* d = &Bs[(nt+1) & 1][0] + brow*264 + bseg*16;
      *(bf16x8*)d = g0;
      *(bf16x8*)(d + 8) = g1;
    }
    if (nt < 30) {
      const __bf16* p = wsrc + (size_t)(nt+2)*4096;
      g0 = *(const bf16x8*)p;
      g1 = *(const bf16x8*)(p + 8);
    }
    int n = nt*16 + col;
    float bias_n = qkvb[256 + n];
    const __bf16* Bb = &Bs[nt & 1][0] + col*264 + quad*8;
    f32x4 acc = zero;
    #pragma unroll
    for (int kk = 0; kk < 8; ++kk) {
      bf16x8 bv = *(const bf16x8*)(Bb + kk*32);
      acc = __builtin_amdgcn_mfma_f32_16x16x32_bf16(af[kk], bv, acc, 0, 0, 0);
    }
    if (nt < 16) {
      #pragma unroll
      for (int r = 0; r < 4; ++r)
        kloc[((size_t)bw*64 + m0 + quad*4 + r)*256 + n] = (__bf16)(acc[r] + bias_n);
    } else {
      bf16x4 o;
      #pragma unroll
      for (int r = 0; r < 4; ++r) o[r] = (__bf16)(acc[r] + bias_n);
      *(bf16x4*)(vloct + ((size_t)bw*256 + (n - 256))*64 + m0 + quad*4) = o;
    }
    __syncthreads();
  }
}

// ---------------- mid/glb KV v2: WT[256+n0..] LDS-staged ----------------
__global__ __launch_bounds__(256) void mg_kv_mfma(
    const __bf16* __restrict__ mgt, const __bf16* __restrict__ WT,
    const float* __restrict__ qkvb,
    __bf16* __restrict__ kmg, __bf16* __restrict__ vmgt)
{
  __shared__ __bf16 Bs[2][16*264];     // 16.5 KB
  int tb = blockIdx.x, nq = blockIdx.y, b = blockIdx.z;   // grid (20,4,2)
  int tid = threadIdx.x, wv = tid >> 6, lane = tid & 63;
  int col = lane & 15, quad = lane >> 4;
  int m0 = tb*64 + wv*16;
  int n0 = nq*128;

  const __bf16* Ab = mgt + ((size_t)b*1280 + m0 + col)*256 + quad*8;
  bf16x8 af[8];
  #pragma unroll
  for (int kk = 0; kk < 8; ++kk) af[kk] = *(const bf16x8*)(Ab + kk*32);

  int brow = tid >> 4, bseg = tid & 15;
  const __bf16* wsrc = WT + ((size_t)(256 + n0 + brow))*256 + bseg*16;
  {
    bf16x8 a0 = *(const bf16x8*)wsrc;
    bf16x8 a1 = *(const bf16x8*)(wsrc + 8);
    __bf16* d = &Bs[0][0] + brow*264 + bseg*16;
    *(bf16x8*)d = a0; *(bf16x8*)(d + 8) = a1;
  }
  bf16x8 g0 = *(const bf16x8*)(wsrc + (size_t)4096);
  bf16x8 g1 = *(const bf16x8*)(wsrc + (size_t)4096 + 8);
  __syncthreads();

  const f32x4 zero = {0.f,0.f,0.f,0.f};
  #pragma unroll 1
  for (int s = 0; s < 8; ++s) {
    if (s < 7) {
      __bf16* d = &Bs[(s+1) & 1][0] + brow*264 + bseg*16;
      *(bf16x8*)d = g0; *(bf16x8*)(d + 8) = g1;
    }
    if (s < 6) {
      const __bf16* p = wsrc + (size_t)(s+2)*4096;
      g0 = *(const bf16x8*)p; g1 = *(const bf16x8*)(p + 8);
    }
    int n = n0 + s*16 + col;
    float bias_n = qkvb[256 + n];
    const __bf16* Bb = &Bs[s & 1][0] + col*264 + quad*8;
    f32x4 acc = zero;
    #pragma unroll
    for (int kk = 0; kk < 8; ++kk) {
      bf16x8 bv = *(const bf16x8*)(Bb + kk*32);
      acc = __builtin_amdgcn_mfma_f32_16x16x32_bf16(af[kk], bv, acc, 0, 0, 0);
    }
    if (n < 256) {
      #pragma unroll
      for (int r = 0; r < 4; ++r)
        kmg[((size_t)b*1280 + m0 + quad*4 + r)*256 + n] = (__bf16)(acc[r] + bias_n);
    } else {
      bf16x4 o;
      #pragma unroll
      for (int r = 0; r < 4; ++r) o[r] = (__bf16)(acc[r] + bias_n);
      *(bf16x4*)(vmgt + ((size_t)b*256 + (n - 256))*1280 + m0 + quad*4) = o;
    }
    __syncthreads();
  }
}

// ---------------- MFMA fused attention: 64-token slab staging ----------------
// K/V staged in 64-token slabs (20 slabs): per slab each thread does ONE coalesced
// b128 global load + ONE b128 LDS write; barriers 42 -> 22. Compute per 32-token
// sub-chunk is identical to the r8 version.
__global__ __launch_bounds__(512) void attn_mfma(
    const __bf16* __restrict__ qbf, const __bf16* __restrict__ kloc,
    const __bf16* __restrict__ vloct, const __bf16* __restrict__ kmg,
    const __bf16* __restrict__ vmgt, __bf16* __restrict__ obf)
{
  __shared__ __bf16 Ks[2][64][40];      // 10 KB: 64 token rows x 32 dims (+pad)
  __shared__ __bf16 Vs[2][32][72];      // 9 KB:  32 dim rows x 64 tokens (+pad)
  __shared__ __bf16 Pb[8][2][16][40];   // 20 KB
  int blk = blockIdx.x;
  int b = blk >> 8, rr = blk & 255;
  int h = rr >> 5, wg = rr & 31;
  int tid = threadIdx.x, wv = tid >> 6, lane = tid & 63;
  int col = lane & 15, quad = lane >> 4;
  int bw = b*256 + wg*8 + wv;           // this wave's window

  // slab staging assignment
  bool isK = tid < 256;
  int krow = tid >> 2,        kseg = tid & 3;          // 64 rows x 4 segs (16 B)
  int vrow = (tid - 256) >> 3, vseg = (tid - 256) & 7; // 32 rows x 8 segs (16 B)
  const __bf16* gbase;
  __bf16 *l0, *l1;
  size_t gslab;
  if (isK) {
    gbase = kmg + ((size_t)(b*1280 + krow))*256 + h*32 + kseg*8;
    gslab = (size_t)64*256;
    l0 = &Ks[0][krow][kseg*8]; l1 = &Ks[1][krow][kseg*8];
  } else {
    gbase = vmgt + ((size_t)(b*256 + h*32 + vrow))*1280 + vseg*8;
    gslab = 64;
    l0 = &Vs[0][vrow][vseg*8]; l1 = &Vs[1][vrow][vseg*8];
  }

  bf16x8 aq = *(const bf16x8*)(qbf + ((size_t)(bw*16 + col))*256 + h*32 + quad*8);
  f32x4 O0 = {0.f,0.f,0.f,0.f}, O1 = {0.f,0.f,0.f,0.f};
  const f32x4 zero = {0.f,0.f,0.f,0.f};
  float ls[4] = {0.f,0.f,0.f,0.f};
  __bf16* PwBase = &Pb[wv][0][0][0];

  // issue slab-0 load early
  bf16x8 sreg = *(const bf16x8*)gbase;

  // ---- local chunks 0,1: per-window global loads ----
  const __bf16* klocb = kloc  + (size_t)bw*16384 + h*32 + quad*8;
  const __bf16* vlocb = vloct + (size_t)bw*16384 + (size_t)(h*32)*64 + quad*8;
  #pragma unroll
  for (int ch = 0; ch < 2; ++ch) {
    bf16x8 k0 = *(const bf16x8*)(klocb + (size_t)(ch*32 + col)*256);
    bf16x8 k1 = *(const bf16x8*)(klocb + (size_t)(ch*32 + 16 + col)*256);
    bf16x8 v0 = *(const bf16x8*)(vlocb + (size_t)col*64 + ch*32);
    bf16x8 v1 = *(const bf16x8*)(vlocb + (size_t)(16+col)*64 + ch*32);
    f32x4 S0 = __builtin_amdgcn_mfma_f32_16x16x32_bf16(aq, k0, zero, 0, 0, 0);
    f32x4 S1 = __builtin_amdgcn_mfma_f32_16x16x32_bf16(aq, k1, zero, 0, 0, 0);
    __bf16* Pw = PwBase + (ch & 1)*640;
    #pragma unroll
    for (int r = 0; r < 4; ++r) {
      float p0 = __builtin_amdgcn_exp2f(S0[r]);
      float p1 = __builtin_amdgcn_exp2f(S1[r]);
      ls[r] += p0 + p1;
      Pw[(quad*4+r)*40 + col]      = (__bf16)p0;
      Pw[(quad*4+r)*40 + 16 + col] = (__bf16)p1;
    }
    bf16x8 ap = *(const bf16x8*)(Pw + (size_t)col*40 + quad*8);
    O0 = __builtin_amdgcn_mfma_f32_16x16x32_bf16(ap, v0, O0, 0, 0, 0);
    O1 = __builtin_amdgcn_mfma_f32_16x16x32_bf16(ap, v1, O1, 0, 0, 0);
  }

  // write slab 0 to buf0, prefetch slab 1
  *(bf16x8*)l0 = sreg;
  sreg = *(const bf16x8*)(gbase + gslab);
  __syncthreads();

  #pragma unroll 1
  for (int s = 0; s < 20; ++s) {
    if (s + 1 < 20) {
      __bf16* ld = (s & 1) ? l0 : l1;     // buffer (s+1)&1
      *(bf16x8*)ld = sreg;
      if (s + 2 < 20) sreg = *(const bf16x8*)(gbase + (size_t)(s+2)*gslab);
    }
    const __bf16* Kb = &Ks[s & 1][0][0];
    const __bf16* Vb = &Vs[s & 1][0][0];
    #pragma unroll
    for (int c = 0; c < 2; ++c) {
      bf16x8 k0 = *(const bf16x8*)(Kb + (c*32 + col)*40 + quad*8);
      bf16x8 k1 = *(const bf16x8*)(Kb + (c*32 + 16 + col)*40 + quad*8);
      bf16x8 v0 = *(const bf16x8*)(Vb + (size_t)col*72 + c*32 + quad*8);
      bf16x8 v1 = *(const bf16x8*)(Vb + (size_t)(16+col)*72 + c*32 + quad*8);
      f32x4 S0 = __builtin_amdgcn_mfma_f32_16x16x32_bf16(aq, k0, zero, 0, 0, 0);
      f32x4 S1 = __builtin_amdgcn_mfma_f32_16x16x32_bf16(aq, k1, zero, 0, 0, 0);
      __bf16* Pw = PwBase + c*640;
      #pragma unroll
      for (int r = 0; r < 4; ++r) {
        float p0 = __builtin_amdgcn_exp2f(S0[r]);
        float p1 = __builtin_amdgcn_exp2f(S1[r]);
        ls[r] += p0 + p1;
        Pw[(quad*4+r)*40 + col]      = (__bf16)p0;
        Pw[(quad*4+r)*40 + 16 + col] = (__bf16)p1;
      }
      bf16x8 ap = *(const bf16x8*)(Pw + (size_t)col*40 + quad*8);
      O0 = __builtin_amdgcn_mfma_f32_16x16x32_bf16(ap, v0, O0, 0, 0, 0);
      O1 = __builtin_amdgcn_mfma_f32_16x16x32_bf16(ap, v1, O1, 0, 0, 0);
    }
    __syncthreads();
  }

  #pragma unroll
  for (int r = 0; r < 4; ++r) {
    #pragma unroll
    for (int m = 1; m < 16; m <<= 1) ls[r] += __shfl_xor(ls[r], m);
  }
  __bf16* op = obf + ((size_t)(bw*16) + quad*4)*256 + h*32 + col;
  #pragma unroll
  for (int r = 0; r < 4; ++r) {
    float inv = 1.f / ls[r];
    op[(size_t)r*256]      = (__bf16)(O0[r]*inv);
    op[(size_t)r*256 + 16] = (__bf16)(O1[r]*inv);
  }
}

// ---------------- out projection v2: WoT tiles LDS-staged ----------------
__global__ __launch_bounds__(256) void gemm_out_strip(
    const __bf16* __restrict__ obf, const __bf16* __restrict__ WoT,
    const float* __restrict__ outb, const float* __restrict__ Fres,
    float* __restrict__ Out)
{
  __shared__ __bf16 Bs4[4*16*264];     // 33 KB: this block's 4 WoT tiles
  __shared__ __bf16 strip[64*264];     // 33 KB
  int blk = blockIdx.x;                // b*64 + wy*4 + cq
  int b = blk >> 6, wy = (blk >> 2) & 15, cq = blk & 3;
  int c0 = cq*64;
  int tid = threadIdx.x, wv = tid >> 6, lane = tid & 63;
  int col = lane & 15, quad = lane >> 4;
  const f32x4 zero = {0.f,0.f,0.f,0.f};

  {
    int brow = tid >> 4, bseg = tid & 15;
    const __bf16* wsrc = WoT + ((size_t)(c0 + brow))*256 + bseg*16;
    #pragma unroll
    for (int s = 0; s < 4; ++s) {
      bf16x8 a0 = *(const bf16x8*)(wsrc + (size_t)s*4096);
      bf16x8 a1 = *(const bf16x8*)(wsrc + (size_t)s*4096 + 8);
      __bf16* d = Bs4 + s*4224 + brow*264 + bseg*16;
      *(bf16x8*)d = a0; *(bf16x8*)(d + 8) = a1;
    }
  }
  __syncthreads();

  #pragma unroll
  for (int i = 0; i < 4; ++i) {
    int wx = wv*4 + i;
    int win = b*256 + wy*16 + wx;
    bf16x8 ao[8];
    const __bf16* op = obf + ((size_t)win*16 + col)*256 + quad*8;
    #pragma unroll
    for (int kk = 0; kk < 8; ++kk) ao[kk] = *(const bf16x8*)(op + kk*32);
    #pragma unroll
    for (int nt = 0; nt < 4; ++nt) {
      const __bf16* Bb = Bs4 + nt*4224 + col*264 + quad*8;
      f32x4 acc = zero;
      #pragma unroll
      for (int kk = 0; kk < 8; ++kk) {
        bf16x8 wf = *(const bf16x8*)(Bb + kk*32);
        acc = __builtin_amdgcn_mfma_f32_16x16x32_bf16(ao[kk], wf, acc, 0, 0, 0);
      }
      bf16x4 o;
      #pragma unroll
      for (int r = 0; r < 4; ++r) o[r] = (__bf16)acc[r];
      *(bf16x4*)&strip[(nt*16+col)*264 + quad*66 + wx*4] = o;
    }
  }
  __syncthreads();
  #pragma unroll
  for (int j = 0; j < 16; ++j) {
    int f4 = j*256 + tid;               // [c][y][xq]
    int xq = f4 & 15, y = (f4 >> 4) & 3, c = f4 >> 6;
    bf16x4 d = *(const bf16x4*)&strip[c*264 + y*66 + xq*4];
    size_t off = ((size_t)(b*256 + c0 + c))*HWSZ + (wy*4 + y)*64 + xq*4;
    float4 r4 = *(const float4*)(Fres + off);
    float bn = outb[c0 + c];
    float4 o;
    o.x = (float)d[0] + bn + r4.x; o.y = (float)d[1] + bn + r4.y;
    o.z = (float)d[2] + bn + r4.z; o.w = (float)d[3] + bn + r4.w;
    *(float4*)(Out + off) = o;
  }
}

extern "C" void kernel_launch(void* const* d_in, const int* in_sizes, int n_in,
                              void* d_out, int out_size, void* d_ws, size_t ws_size,
                              hipStream_t stream) {
  const float* F     = (const float*)d_in[0];
  const float* qkv_w = (const float*)d_in[1];
  const float* qkv_b = (const float*)d_in[2];
  const float* out_w = (const float*)d_in[3];
  const float* out_b = (const float*)d_in[4];
  const float* ln_w  = (const float*)d_in[5];
  const float* ln_b  = (const float*)d_in[6];
  float* out = (float*)d_out;

  __bf16* qnb   = (__bf16*)d_ws;             // 2,097,152 h
  __bf16* qbf   = qnb   + 2097152;           // 2,097,152 h
  __bf16* obf   = qbf   + 2097152;           // 2,097,152 h
  __bf16* kloc  = obf   + 2097152;           // 8,388,608 h
  __bf16* vloct = kloc  + 8388608;           // 8,388,608 h
  __bf16* kmg   = vloct + 8388608;           // 655,360 h
  __bf16* vmgt  = kmg   + 655360;            // 655,360 h
  __bf16* mgt   = vmgt  + 655360;            // 655,360 h
  __bf16* WT    = mgt   + 655360;            // 196,608 h
  __bf16* WoT   = WT    + 196608;            // 65,536 h
  float*  mid   = (float*)(WoT + 65536);     // 524,288 f
  float*  glb   = mid   + 524288;            // 131,072 f

  ln_qn_kernel<<<512, 256, 0, stream>>>(F, ln_w, ln_b, qnb);
  pool_kernel<<<512, 256, 0, stream>>>(F, mid, glb);
  transpose_all<<<dim3(56, 4), 256, 0, stream>>>(qkv_w, out_w, mid, glb, WT, WoT, mgt);
  gemm_q_mfma<<<256, 256, 0, stream>>>(qnb, WT, qkv_b, qbf);
  loc_kv_mfma<<<512, 256, 0, stream>>>(F, WT, qkv_b, kloc, vloct);
  mg_kv_mfma<<<dim3(20, 4, 2), 256, 0, stream>>>(mgt, WT, qkv_b, kmg, vmgt);
  attn_mfma<<<512, 512, 0, stream>>>(qbf, kloc, vloct, kmg, vmgt, obf);
  gemm_out_strip<<<128, 256, 0, stream>>>(obf, WoT, out_b, F, out);
}